// Round 1
// baseline (2218.170 us; speedup 1.0000x reference)
//
#include <hip/hip_runtime.h>
#include <hip/hip_bf16.h>
#include <math.h>

#define N_NODES 100000
#define N_EDGES 1600000
#define N_FEAT 64
#define HID 64
#define HL 256
#define N_GRAPHS 512

__device__ __forceinline__ float rlf(float v, int l) {
    return __int_as_float(__builtin_amdgcn_readlane(__float_as_int(v), l));
}

// ---------------- CSR build ----------------

__global__ void k_hist(const int* __restrict__ dst, int* __restrict__ cnt, int e) {
    int i = blockIdx.x * blockDim.x + threadIdx.x;
    if (i < e) atomicAdd(&cnt[dst[i]], 1);
}

// block scans 1024 elements (256 threads x 4)
__global__ void k_scan1(const int* __restrict__ cnt, int* __restrict__ rowptr,
                        int* __restrict__ bsum, int n) {
    __shared__ int sdata[256];
    int t = threadIdx.x;
    int base = blockIdx.x * 1024 + t * 4;
    int v[4];
    int s = 0;
#pragma unroll
    for (int j = 0; j < 4; j++) {
        int idx = base + j;
        v[j] = (idx < n) ? cnt[idx] : 0;
        s += v[j];
    }
    sdata[t] = s;
    __syncthreads();
    for (int off = 1; off < 256; off <<= 1) {
        int x = sdata[t];
        int y = (t >= off) ? sdata[t - off] : 0;
        __syncthreads();
        sdata[t] = x + y;
        __syncthreads();
    }
    int incl = sdata[t];
    int excl = incl - s;
    if (t == 255) bsum[blockIdx.x] = incl;
    int run = excl;
#pragma unroll
    for (int j = 0; j < 4; j++) {
        int idx = base + j;
        if (idx < n) rowptr[idx] = run;
        run += v[j];
    }
}

__global__ void k_scan2(int* __restrict__ bsum, int nb) {
    __shared__ int sdata[128];
    int t = threadIdx.x;
    int v = (t < nb) ? bsum[t] : 0;
    sdata[t] = v;
    __syncthreads();
    for (int off = 1; off < 128; off <<= 1) {
        int x = sdata[t];
        int y = (t >= off) ? sdata[t - off] : 0;
        __syncthreads();
        sdata[t] = x + y;
        __syncthreads();
    }
    if (t < nb) bsum[t] = sdata[t] - v;  // exclusive
}

__global__ void k_scan3(int* __restrict__ rowptr, int* __restrict__ cursor,
                        const int* __restrict__ bsum, int n, int e) {
    int i = blockIdx.x * blockDim.x + threadIdx.x;
    if (i == 0) rowptr[n] = e;
    if (i < n) {
        int val = rowptr[i] + bsum[i >> 10];
        rowptr[i] = val;
        cursor[i] = val;
    }
}

__global__ void k_scatter(const int* __restrict__ src, const int* __restrict__ dst,
                          int* __restrict__ cursor, int* __restrict__ ssrc, int e) {
    int i = blockIdx.x * blockDim.x + threadIdx.x;
    if (i < e) {
        int d = dst[i];
        int p = atomicAdd(&cursor[d], 1);
        ssrc[p] = src[i];
    }
}

// ---------------- fused conv: out = agg@wrel + brel + h@wroot ----------------
// one wave per node; lane l owns feature column l; weight columns in VGPRs.

template <int RELU>
__global__ __launch_bounds__(256, 2) void k_conv(
    const float* __restrict__ hin, float* __restrict__ hout,
    const int* __restrict__ rowptr, const int* __restrict__ ssrc,
    const float* __restrict__ wrel, const float* __restrict__ brel,
    const float* __restrict__ wroot, int n) {
    int lane = threadIdx.x & 63;
    int wid = (blockIdx.x * blockDim.x + threadIdx.x) >> 6;
    int nw = (gridDim.x * blockDim.x) >> 6;

    float wr[64], wq[64];
#pragma unroll
    for (int k = 0; k < 64; k++) {
        wr[k] = wrel[k * 64 + lane];
        wq[k] = wroot[k * 64 + lane];
    }
    float bl = brel[lane];

    for (int i = wid; i < n; i += nw) {
        float hl = hin[(size_t)i * 64 + lane];
        float agg = 0.f;
        int e0 = rowptr[i], e1 = rowptr[i + 1];
        for (int e = e0; e < e1; e++) {
            int j = ssrc[e];
            agg += hin[(size_t)j * 64 + lane];
        }
        float y = bl;
#pragma unroll
        for (int k = 0; k < 64; k++) {
            y += rlf(agg, k) * wr[k];
            y += rlf(hl, k) * wq[k];
        }
        if (RELU) y = fmaxf(y, 0.f);
        hout[(size_t)i * 64 + lane] = y;
    }
}

// ---------------- pooling ----------------

__global__ void k_bounds(const int* __restrict__ batch, int* __restrict__ gstart,
                         int* __restrict__ gend, int n) {
    int i = blockIdx.x * blockDim.x + threadIdx.x;
    if (i < n) {
        int b = batch[i];
        if (i == 0 || batch[i - 1] != b) gstart[b] = i;
        if (i == n - 1 || batch[i + 1] != b) gend[b] = i + 1;
    }
}

__global__ void k_pool(const float* __restrict__ h, const int* __restrict__ gstart,
                       const int* __restrict__ gend, const float* __restrict__ T,
                       float* __restrict__ pool) {
    int g = blockIdx.x;
    int l = threadIdx.x;  // 64 threads
    int s0 = gstart[g], s1 = gend[g];
    float s = 0.f, mx = -INFINITY;
    for (int n = s0; n < s1; n++) {
        float v = h[(size_t)n * 64 + l];
        s += v;
        mx = fmaxf(mx, v);
    }
    int cnt = s1 - s0;
    float mean = s / fmaxf((float)cnt, 1.f);
    if (cnt == 0) mx = 0.f;
    float* row = pool + (size_t)g * 193;
    row[l] = mx;
    row[64 + l] = mean;
    row[128 + l] = s;
    if (l == 0) row[192] = T[g];
}

// ---------------- MLP head ----------------

__global__ __launch_bounds__(256) void k_mlp(
    const float* __restrict__ pool, const float* __restrict__ w1,
    const float* __restrict__ b1, const float* __restrict__ w2,
    const float* __restrict__ b2, const float* __restrict__ w3,
    const float* __restrict__ b3, float* __restrict__ out) {
    __shared__ float sin_[193];
    __shared__ float so1[256];
    __shared__ float red[256];
    int g = blockIdx.x, t = threadIdx.x;
    if (t < 193) sin_[t] = pool[(size_t)g * 193 + t];
    __syncthreads();
    float a = b1[t];
    for (int k = 0; k < 193; k++) a += sin_[k] * w1[k * 256 + t];
    a = fmaxf(a, 0.f);
    so1[t] = a;
    __syncthreads();
    float a2 = b2[t];
    for (int k = 0; k < 256; k++) a2 += so1[k] * w2[k * 256 + t];
    a2 = fmaxf(a2, 0.f);
    red[t] = a2 * w3[t];
    __syncthreads();
    for (int s = 128; s > 0; s >>= 1) {
        if (t < s) red[t] += red[t + s];
        __syncthreads();
    }
    if (t == 0) out[g] = red[0] + b3[0];
}

extern "C" void kernel_launch(void* const* d_in, const int* in_sizes, int n_in,
                              void* d_out, int out_size, void* d_ws, size_t ws_size,
                              hipStream_t stream) {
    const int N = N_NODES, E = N_EDGES, G = N_GRAPHS;

    const float* x = (const float*)d_in[0];
    const int* ei = (const int*)d_in[1];
    const int* batch = (const int*)d_in[2];
    const float* T = (const float*)d_in[3];
    const float* wrel[4] = {(const float*)d_in[4], (const float*)d_in[7],
                            (const float*)d_in[10], (const float*)d_in[13]};
    const float* brel[4] = {(const float*)d_in[5], (const float*)d_in[8],
                            (const float*)d_in[11], (const float*)d_in[14]};
    const float* wroot[4] = {(const float*)d_in[6], (const float*)d_in[9],
                             (const float*)d_in[12], (const float*)d_in[15]};
    const float* w1 = (const float*)d_in[16];
    const float* b1 = (const float*)d_in[17];
    const float* w2 = (const float*)d_in[18];
    const float* b2 = (const float*)d_in[19];
    const float* w3 = (const float*)d_in[20];
    const float* b3 = (const float*)d_in[21];
    float* out = (float*)d_out;

    const int* esrc = ei;
    const int* edst = ei + E;

    // workspace layout
    char* ws = (char*)d_ws;
    size_t off = 0;
    auto alloc = [&](size_t bytes) {
        size_t r = off;
        off = (off + bytes + 255) & ~(size_t)255;
        return r;
    };
    int* cnt = (int*)(ws + alloc((size_t)N * 4));
    int* rowptr = (int*)(ws + alloc((size_t)(N + 1) * 4));
    int* cursor = (int*)(ws + alloc((size_t)N * 4));
    int* bsum = (int*)(ws + alloc(512));
    int* ssrc = (int*)(ws + alloc((size_t)E * 4));
    float* h0 = (float*)(ws + alloc((size_t)N * 64 * 4));
    float* h1 = (float*)(ws + alloc((size_t)N * 64 * 4));
    int* gstart = (int*)(ws + alloc((size_t)G * 4));
    int* gend = (int*)(ws + alloc((size_t)G * 4));
    float* pool = (float*)(ws + alloc((size_t)G * 193 * 4));

    // 1. CSR build
    hipMemsetAsync(cnt, 0, (size_t)N * 4, stream);
    hipMemsetAsync(gstart, 0, (size_t)G * 4, stream);
    hipMemsetAsync(gend, 0, (size_t)G * 4, stream);
    k_hist<<<(E + 255) / 256, 256, 0, stream>>>(edst, cnt, E);
    int nb1 = (N + 1023) / 1024;
    k_scan1<<<nb1, 256, 0, stream>>>(cnt, rowptr, bsum, N);
    k_scan2<<<1, 128, 0, stream>>>(bsum, nb1);
    k_scan3<<<(N + 255) / 256, 256, 0, stream>>>(rowptr, cursor, bsum, N, E);
    k_scatter<<<(E + 255) / 256, 256, 0, stream>>>(esrc, edst, cursor, ssrc, E);

    // 2. four conv layers (ping-pong h buffers)
    const int CONV_BLOCKS = 1024;
    k_conv<1><<<CONV_BLOCKS, 256, 0, stream>>>(x, h0, rowptr, ssrc, wrel[0], brel[0], wroot[0], N);
    k_conv<1><<<CONV_BLOCKS, 256, 0, stream>>>(h0, h1, rowptr, ssrc, wrel[1], brel[1], wroot[1], N);
    k_conv<1><<<CONV_BLOCKS, 256, 0, stream>>>(h1, h0, rowptr, ssrc, wrel[2], brel[2], wroot[2], N);
    k_conv<0><<<CONV_BLOCKS, 256, 0, stream>>>(h0, h1, rowptr, ssrc, wrel[3], brel[3], wroot[3], N);

    // 3. pooling
    k_bounds<<<(N + 255) / 256, 256, 0, stream>>>(batch, gstart, gend, N);
    k_pool<<<G, 64, 0, stream>>>(h1, gstart, gend, T, pool);

    // 4. MLP head
    k_mlp<<<G, 256, 0, stream>>>(pool, w1, b1, w2, b2, w3, b3, out);
}

// Round 2
// 963.170 us; speedup vs baseline: 2.3030x; 2.3030x over previous
//
#include <hip/hip_runtime.h>
#include <hip/hip_bf16.h>
#include <math.h>

#define N_NODES 100000
#define N_EDGES 1600000
#define N_FEAT 64
#define HID 64
#define HL 256
#define N_GRAPHS 512

// ---------------- CSR build ----------------

__global__ void k_hist(const int* __restrict__ dst, int* __restrict__ cnt, int e) {
    int i = blockIdx.x * blockDim.x + threadIdx.x;
    if (i < e) atomicAdd(&cnt[dst[i]], 1);
}

// block scans 1024 elements (256 threads x 4)
__global__ void k_scan1(const int* __restrict__ cnt, int* __restrict__ rowptr,
                        int* __restrict__ bsum, int n) {
    __shared__ int sdata[256];
    int t = threadIdx.x;
    int base = blockIdx.x * 1024 + t * 4;
    int v[4];
    int s = 0;
#pragma unroll
    for (int j = 0; j < 4; j++) {
        int idx = base + j;
        v[j] = (idx < n) ? cnt[idx] : 0;
        s += v[j];
    }
    sdata[t] = s;
    __syncthreads();
    for (int off = 1; off < 256; off <<= 1) {
        int x = sdata[t];
        int y = (t >= off) ? sdata[t - off] : 0;
        __syncthreads();
        sdata[t] = x + y;
        __syncthreads();
    }
    int incl = sdata[t];
    int excl = incl - s;
    if (t == 255) bsum[blockIdx.x] = incl;
    int run = excl;
#pragma unroll
    for (int j = 0; j < 4; j++) {
        int idx = base + j;
        if (idx < n) rowptr[idx] = run;
        run += v[j];
    }
}

__global__ void k_scan2(int* __restrict__ bsum, int nb) {
    __shared__ int sdata[128];
    int t = threadIdx.x;
    int v = (t < nb) ? bsum[t] : 0;
    sdata[t] = v;
    __syncthreads();
    for (int off = 1; off < 128; off <<= 1) {
        int x = sdata[t];
        int y = (t >= off) ? sdata[t - off] : 0;
        __syncthreads();
        sdata[t] = x + y;
        __syncthreads();
    }
    if (t < nb) bsum[t] = sdata[t] - v;  // exclusive
}

__global__ void k_scan3(int* __restrict__ rowptr, int* __restrict__ cursor,
                        const int* __restrict__ bsum, int n, int e) {
    int i = blockIdx.x * blockDim.x + threadIdx.x;
    if (i == 0) rowptr[n] = e;
    if (i < n) {
        int val = rowptr[i] + bsum[i >> 10];
        rowptr[i] = val;
        cursor[i] = val;
    }
}

__global__ void k_scatter(const int* __restrict__ src, const int* __restrict__ dst,
                          int* __restrict__ cursor, int* __restrict__ ssrc, int e) {
    int i = blockIdx.x * blockDim.x + threadIdx.x;
    if (i < e) {
        int d = dst[i];
        int p = atomicAdd(&cursor[d], 1);
        ssrc[p] = src[i];
    }
}

// ---------------- aggregation: agg[i] = sum_{j->i} h[j] ----------------
// one wave per node, lane = feature. Edge loop unrolled x4 so 4 independent
// 256B row-gathers are in flight; indices are wave-uniform (scalar loads).

__global__ __launch_bounds__(256) void k_agg(
    const float* __restrict__ hin, float* __restrict__ agg,
    const int* __restrict__ rowptr, const int* __restrict__ ssrc, int n) {
    int lane = threadIdx.x & 63;
    int i = (blockIdx.x * 256 + threadIdx.x) >> 6;
    if (i >= n) return;
    int e0 = rowptr[i], e1 = rowptr[i + 1];
    float a0 = 0.f, a1 = 0.f, a2 = 0.f, a3 = 0.f;
    int e = e0;
    for (; e + 4 <= e1; e += 4) {
        int j0 = ssrc[e], j1 = ssrc[e + 1], j2 = ssrc[e + 2], j3 = ssrc[e + 3];
        a0 += hin[(size_t)j0 * 64 + lane];
        a1 += hin[(size_t)j1 * 64 + lane];
        a2 += hin[(size_t)j2 * 64 + lane];
        a3 += hin[(size_t)j3 * 64 + lane];
    }
    for (; e < e1; e++) a0 += hin[(size_t)ssrc[e] * 64 + lane];
    agg[(size_t)i * 64 + lane] = (a0 + a1) + (a2 + a3);
}

// ---------------- dense fused: out = [relu](h@wroot + agg@wrel + brel) -----
// node per LANE: each lane keeps its node's h row + agg row in VGPRs (128
// regs). Weight indices are wave-uniform -> scalar loads (s_load) feeding
// SGPR-operand v_fma at full rate. 8 independent acc chains for ILP.

template <int RELU>
__global__ __launch_bounds__(64) void k_gemm(
    const float* __restrict__ h, const float* __restrict__ agg,
    const float* __restrict__ wroot, const float* __restrict__ wrel,
    const float* __restrict__ brel, float* __restrict__ out, int n) {
    int t = blockIdx.x * 64 + threadIdx.x;
    if (t >= n) return;
    float hr[64], ar[64];
    const float4* hp = (const float4*)(h + (size_t)t * 64);
    const float4* ap = (const float4*)(agg + (size_t)t * 64);
#pragma unroll
    for (int q = 0; q < 16; q++) {
        float4 v = hp[q];
        hr[4 * q] = v.x; hr[4 * q + 1] = v.y; hr[4 * q + 2] = v.z; hr[4 * q + 3] = v.w;
        float4 u = ap[q];
        ar[4 * q] = u.x; ar[4 * q + 1] = u.y; ar[4 * q + 2] = u.z; ar[4 * q + 3] = u.w;
    }
    float* op = out + (size_t)t * 64;
    for (int o = 0; o < 64; o += 4) {
        float acc[4], acd[4];
#pragma unroll
        for (int j = 0; j < 4; j++) {
            acc[j] = brel[o + j];
            acd[j] = 0.f;
        }
#pragma unroll
        for (int k = 0; k < 64; k++) {
            float hk = hr[k], ak = ar[k];
#pragma unroll
            for (int j = 0; j < 4; j++) {
                acc[j] += hk * wroot[k * 64 + o + j];
                acd[j] += ak * wrel[k * 64 + o + j];
            }
        }
        float4 r;
        r.x = acc[0] + acd[0];
        r.y = acc[1] + acd[1];
        r.z = acc[2] + acd[2];
        r.w = acc[3] + acd[3];
        if (RELU) {
            r.x = fmaxf(r.x, 0.f); r.y = fmaxf(r.y, 0.f);
            r.z = fmaxf(r.z, 0.f); r.w = fmaxf(r.w, 0.f);
        }
        *(float4*)(op + o) = r;
    }
}

// ---------------- pooling ----------------

__global__ void k_bounds(const int* __restrict__ batch, int* __restrict__ gstart,
                         int* __restrict__ gend, int n) {
    int i = blockIdx.x * blockDim.x + threadIdx.x;
    if (i < n) {
        int b = batch[i];
        if (i == 0 || batch[i - 1] != b) gstart[b] = i;
        if (i == n - 1 || batch[i + 1] != b) gend[b] = i + 1;
    }
}

__global__ void k_pool(const float* __restrict__ h, const int* __restrict__ gstart,
                       const int* __restrict__ gend, const float* __restrict__ T,
                       float* __restrict__ pool) {
    int g = blockIdx.x;
    int l = threadIdx.x;  // 64 threads
    int s0 = gstart[g], s1 = gend[g];
    float s0a = 0.f, s1a = 0.f, s2a = 0.f, s3a = 0.f;
    float m0 = -INFINITY, m1 = -INFINITY, m2 = -INFINITY, m3 = -INFINITY;
    int n = s0;
    for (; n + 4 <= s1; n += 4) {
        float v0 = h[(size_t)n * 64 + l];
        float v1 = h[(size_t)(n + 1) * 64 + l];
        float v2 = h[(size_t)(n + 2) * 64 + l];
        float v3 = h[(size_t)(n + 3) * 64 + l];
        s0a += v0; s1a += v1; s2a += v2; s3a += v3;
        m0 = fmaxf(m0, v0); m1 = fmaxf(m1, v1);
        m2 = fmaxf(m2, v2); m3 = fmaxf(m3, v3);
    }
    for (; n < s1; n++) {
        float v = h[(size_t)n * 64 + l];
        s0a += v;
        m0 = fmaxf(m0, v);
    }
    float s = (s0a + s1a) + (s2a + s3a);
    float mx = fmaxf(fmaxf(m0, m1), fmaxf(m2, m3));
    int cnt = s1 - s0;
    float mean = s / fmaxf((float)cnt, 1.f);
    if (cnt == 0) mx = 0.f;
    float* row = pool + (size_t)g * 193;
    row[l] = mx;
    row[64 + l] = mean;
    row[128 + l] = s;
    if (l == 0) row[192] = T[g];
}

// ---------------- MLP head ----------------

__global__ __launch_bounds__(256) void k_mlp(
    const float* __restrict__ pool, const float* __restrict__ w1,
    const float* __restrict__ b1, const float* __restrict__ w2,
    const float* __restrict__ b2, const float* __restrict__ w3,
    const float* __restrict__ b3, float* __restrict__ out) {
    __shared__ float sin_[193];
    __shared__ float so1[256];
    __shared__ float red[256];
    int g = blockIdx.x, t = threadIdx.x;
    if (t < 193) sin_[t] = pool[(size_t)g * 193 + t];
    __syncthreads();
    float a = b1[t];
    for (int k = 0; k < 193; k++) a += sin_[k] * w1[k * 256 + t];
    a = fmaxf(a, 0.f);
    so1[t] = a;
    __syncthreads();
    float a2 = b2[t];
    for (int k = 0; k < 256; k++) a2 += so1[k] * w2[k * 256 + t];
    a2 = fmaxf(a2, 0.f);
    red[t] = a2 * w3[t];
    __syncthreads();
    for (int s = 128; s > 0; s >>= 1) {
        if (t < s) red[t] += red[t + s];
        __syncthreads();
    }
    if (t == 0) out[g] = red[0] + b3[0];
}

extern "C" void kernel_launch(void* const* d_in, const int* in_sizes, int n_in,
                              void* d_out, int out_size, void* d_ws, size_t ws_size,
                              hipStream_t stream) {
    const int N = N_NODES, E = N_EDGES, G = N_GRAPHS;

    const float* x = (const float*)d_in[0];
    const int* ei = (const int*)d_in[1];
    const int* batch = (const int*)d_in[2];
    const float* T = (const float*)d_in[3];
    const float* wrel[4] = {(const float*)d_in[4], (const float*)d_in[7],
                            (const float*)d_in[10], (const float*)d_in[13]};
    const float* brel[4] = {(const float*)d_in[5], (const float*)d_in[8],
                            (const float*)d_in[11], (const float*)d_in[14]};
    const float* wroot[4] = {(const float*)d_in[6], (const float*)d_in[9],
                             (const float*)d_in[12], (const float*)d_in[15]};
    const float* w1 = (const float*)d_in[16];
    const float* b1 = (const float*)d_in[17];
    const float* w2 = (const float*)d_in[18];
    const float* b2 = (const float*)d_in[19];
    const float* w3 = (const float*)d_in[20];
    const float* b3 = (const float*)d_in[21];
    float* out = (float*)d_out;

    const int* esrc = ei;
    const int* edst = ei + E;

    // workspace layout
    char* ws = (char*)d_ws;
    size_t off = 0;
    auto alloc = [&](size_t bytes) {
        size_t r = off;
        off = (off + bytes + 255) & ~(size_t)255;
        return r;
    };
    int* cnt = (int*)(ws + alloc((size_t)N * 4));
    int* rowptr = (int*)(ws + alloc((size_t)(N + 1) * 4));
    int* cursor = (int*)(ws + alloc((size_t)N * 4));
    int* bsum = (int*)(ws + alloc(512));
    int* ssrc = (int*)(ws + alloc((size_t)E * 4));
    float* h0 = (float*)(ws + alloc((size_t)N * 64 * 4));
    float* h1 = (float*)(ws + alloc((size_t)N * 64 * 4));
    float* agg = (float*)(ws + alloc((size_t)N * 64 * 4));
    int* gstart = (int*)(ws + alloc((size_t)G * 4));
    int* gend = (int*)(ws + alloc((size_t)G * 4));
    float* pool = (float*)(ws + alloc((size_t)G * 193 * 4));

    // 1. CSR build
    hipMemsetAsync(cnt, 0, (size_t)N * 4, stream);
    hipMemsetAsync(gstart, 0, (size_t)G * 4, stream);
    hipMemsetAsync(gend, 0, (size_t)G * 4, stream);
    k_hist<<<(E + 255) / 256, 256, 0, stream>>>(edst, cnt, E);
    int nb1 = (N + 1023) / 1024;
    k_scan1<<<nb1, 256, 0, stream>>>(cnt, rowptr, bsum, N);
    k_scan2<<<1, 128, 0, stream>>>(bsum, nb1);
    k_scan3<<<(N + 255) / 256, 256, 0, stream>>>(rowptr, cursor, bsum, N, E);
    k_scatter<<<(E + 255) / 256, 256, 0, stream>>>(esrc, edst, cursor, ssrc, E);

    // 2. four conv layers = (agg, dense) pairs, ping-pong h buffers
    int agg_blocks = (N * 64 + 255) / 256;   // one wave per node
    int gemm_blocks = (N + 63) / 64;         // one lane per node

    k_agg<<<agg_blocks, 256, 0, stream>>>(x, agg, rowptr, ssrc, N);
    k_gemm<1><<<gemm_blocks, 64, 0, stream>>>(x, agg, wroot[0], wrel[0], brel[0], h0, N);

    k_agg<<<agg_blocks, 256, 0, stream>>>(h0, agg, rowptr, ssrc, N);
    k_gemm<1><<<gemm_blocks, 64, 0, stream>>>(h0, agg, wroot[1], wrel[1], brel[1], h1, N);

    k_agg<<<agg_blocks, 256, 0, stream>>>(h1, agg, rowptr, ssrc, N);
    k_gemm<1><<<gemm_blocks, 64, 0, stream>>>(h1, agg, wroot[2], wrel[2], brel[2], h0, N);

    k_agg<<<agg_blocks, 256, 0, stream>>>(h0, agg, rowptr, ssrc, N);
    k_gemm<0><<<gemm_blocks, 64, 0, stream>>>(h0, agg, wroot[3], wrel[3], brel[3], h1, N);

    // 3. pooling
    k_bounds<<<(N + 255) / 256, 256, 0, stream>>>(batch, gstart, gend, N);
    k_pool<<<G, 64, 0, stream>>>(h1, gstart, gend, T, pool);

    // 4. MLP head
    k_mlp<<<G, 256, 0, stream>>>(pool, w1, b1, w2, b2, w3, b3, out);
}

// Round 3
// 775.144 us; speedup vs baseline: 2.8616x; 1.2426x over previous
//
#include <hip/hip_runtime.h>
#include <hip/hip_bf16.h>
#include <math.h>

#define N_NODES 100000
#define N_EDGES 1600000
#define N_FEAT 64
#define HID 64
#define HL 256
#define N_GRAPHS 512

// ---------------- CSR build ----------------

__global__ void k_hist(const int* __restrict__ dst, int* __restrict__ cnt, int e) {
    int i = blockIdx.x * blockDim.x + threadIdx.x;
    if (i < e) atomicAdd(&cnt[dst[i]], 1);
}

// block scans 1024 elements (256 threads x 4)
__global__ void k_scan1(const int* __restrict__ cnt, int* __restrict__ rowptr,
                        int* __restrict__ bsum, int n) {
    __shared__ int sdata[256];
    int t = threadIdx.x;
    int base = blockIdx.x * 1024 + t * 4;
    int v[4];
    int s = 0;
#pragma unroll
    for (int j = 0; j < 4; j++) {
        int idx = base + j;
        v[j] = (idx < n) ? cnt[idx] : 0;
        s += v[j];
    }
    sdata[t] = s;
    __syncthreads();
    for (int off = 1; off < 256; off <<= 1) {
        int x = sdata[t];
        int y = (t >= off) ? sdata[t - off] : 0;
        __syncthreads();
        sdata[t] = x + y;
        __syncthreads();
    }
    int incl = sdata[t];
    int excl = incl - s;
    if (t == 255) bsum[blockIdx.x] = incl;
    int run = excl;
#pragma unroll
    for (int j = 0; j < 4; j++) {
        int idx = base + j;
        if (idx < n) rowptr[idx] = run;
        run += v[j];
    }
}

__global__ void k_scan2(int* __restrict__ bsum, int nb) {
    __shared__ int sdata[128];
    int t = threadIdx.x;
    int v = (t < nb) ? bsum[t] : 0;
    sdata[t] = v;
    __syncthreads();
    for (int off = 1; off < 128; off <<= 1) {
        int x = sdata[t];
        int y = (t >= off) ? sdata[t - off] : 0;
        __syncthreads();
        sdata[t] = x + y;
        __syncthreads();
    }
    if (t < nb) bsum[t] = sdata[t] - v;  // exclusive
}

__global__ void k_scan3(int* __restrict__ rowptr, int* __restrict__ cursor,
                        const int* __restrict__ bsum, int n, int e) {
    int i = blockIdx.x * blockDim.x + threadIdx.x;
    if (i == 0) rowptr[n] = e;
    if (i < n) {
        int val = rowptr[i] + bsum[i >> 10];
        rowptr[i] = val;
        cursor[i] = val;
    }
}

__global__ void k_scatter(const int* __restrict__ src, const int* __restrict__ dst,
                          int* __restrict__ cursor, int* __restrict__ ssrc, int e) {
    int i = blockIdx.x * blockDim.x + threadIdx.x;
    if (i < e) {
        int d = dst[i];
        int p = atomicAdd(&cursor[d], 1);
        ssrc[p] = src[i];
    }
}

// ---------------- aggregation: agg[i] = sum_{j->i} h[j] ----------------
// one wave per node, lane = feature. Edge loop unrolled x4 so 4 independent
// 256B row-gathers are in flight; indices are wave-uniform (scalar loads).

__global__ __launch_bounds__(256) void k_agg(
    const float* __restrict__ hin, float* __restrict__ agg,
    const int* __restrict__ rowptr, const int* __restrict__ ssrc, int n) {
    int lane = threadIdx.x & 63;
    int i = (blockIdx.x * 256 + threadIdx.x) >> 6;
    if (i >= n) return;
    int e0 = rowptr[i], e1 = rowptr[i + 1];
    float a0 = 0.f, a1 = 0.f, a2 = 0.f, a3 = 0.f;
    int e = e0;
    for (; e + 4 <= e1; e += 4) {
        int j0 = ssrc[e], j1 = ssrc[e + 1], j2 = ssrc[e + 2], j3 = ssrc[e + 3];
        a0 += hin[(size_t)j0 * 64 + lane];
        a1 += hin[(size_t)j1 * 64 + lane];
        a2 += hin[(size_t)j2 * 64 + lane];
        a3 += hin[(size_t)j3 * 64 + lane];
    }
    for (; e < e1; e++) a0 += hin[(size_t)ssrc[e] * 64 + lane];
    agg[(size_t)i * 64 + lane] = (a0 + a1) + (a2 + a3);
}

// ---------------- dense fused: out = [relu](h@wroot + agg@wrel + brel) -----
// LDS-staged register-tiled GEMM. Block = 256 threads = 64-node tile, N=64,
// K=128 as two 64-phases (h@wroot then agg@wrel). Weights (32 KB) in LDS
// once; x-tile (64x64, stride 68 pad) per phase. Each thread: 4 nodes x 4
// outputs. Per 4-k chunk: 8 ds_read_b128 vs 64 v_fma -> VALU-bound.

#define SX_LD 68

template <int RELU>
__global__ __launch_bounds__(256) void k_gemm(
    const float* __restrict__ h, const float* __restrict__ agg,
    const float* __restrict__ wroot, const float* __restrict__ wrel,
    const float* __restrict__ brel, float* __restrict__ out, int n) {
    __shared__ float sw[128 * 64];   // rows 0-63: wroot, 64-127: wrel (row=k, col=o)
    __shared__ float sx[64 * SX_LD]; // x tile, padded leading dim

    int tid = threadIdx.x;
    int tm = tid >> 4;   // node group 0..15 (4 nodes each)
    int tn = tid & 15;   // output group 0..15 (4 outputs each)
    int m0 = blockIdx.x * 64;

    // stage both weight matrices: 2 x 4096 floats = 2 x 1024 float4
    {
        const float4* a = (const float4*)wroot;
        const float4* b = (const float4*)wrel;
        float4* s = (float4*)sw;
#pragma unroll
        for (int r = 0; r < 4; r++) s[tid + 256 * r] = a[tid + 256 * r];
#pragma unroll
        for (int r = 0; r < 4; r++) s[1024 + tid + 256 * r] = b[tid + 256 * r];
    }

    float acc[4][4];
#pragma unroll
    for (int i = 0; i < 4; i++)
#pragma unroll
        for (int j = 0; j < 4; j++) acc[i][j] = 0.f;

    for (int phase = 0; phase < 2; phase++) {
        const float* src = phase ? agg : h;
        __syncthreads();  // phase0: weights visible; phase1: sx no longer read
        // stage x tile: 64 nodes x 64 floats (coalesced float4)
#pragma unroll
        for (int r = 0; r < 4; r++) {
            int f = tid + 256 * r;           // float4 index in tile
            int node = f >> 4, kc = f & 15;
            int gnode = m0 + node;
            float4 v = make_float4(0.f, 0.f, 0.f, 0.f);
            if (gnode < n) v = ((const float4*)(src + (size_t)gnode * 64))[kc];
            *(float4*)(sx + node * SX_LD + kc * 4) = v;
        }
        __syncthreads();

        const float* wbase = sw + phase * 64 * 64;
#pragma unroll
        for (int kc = 0; kc < 16; kc++) {
            float4 xv[4], wv[4];
#pragma unroll
            for (int i = 0; i < 4; i++)
                xv[i] = *(const float4*)(sx + (tm * 4 + i) * SX_LD + kc * 4);
#pragma unroll
            for (int kk = 0; kk < 4; kk++)
                wv[kk] = *(const float4*)(wbase + (kc * 4 + kk) * 64 + tn * 4);
#pragma unroll
            for (int i = 0; i < 4; i++) {
                float xs0 = xv[i].x, xs1 = xv[i].y, xs2 = xv[i].z, xs3 = xv[i].w;
                acc[i][0] += xs0 * wv[0].x + xs1 * wv[1].x + xs2 * wv[2].x + xs3 * wv[3].x;
                acc[i][1] += xs0 * wv[0].y + xs1 * wv[1].y + xs2 * wv[2].y + xs3 * wv[3].y;
                acc[i][2] += xs0 * wv[0].z + xs1 * wv[1].z + xs2 * wv[2].z + xs3 * wv[3].z;
                acc[i][3] += xs0 * wv[0].w + xs1 * wv[1].w + xs2 * wv[2].w + xs3 * wv[3].w;
            }
        }
    }

    // epilogue
    float4 bb = *(const float4*)(brel + tn * 4);
#pragma unroll
    for (int i = 0; i < 4; i++) {
        int node = m0 + tm * 4 + i;
        if (node < n) {
            float4 r;
            r.x = acc[i][0] + bb.x;
            r.y = acc[i][1] + bb.y;
            r.z = acc[i][2] + bb.z;
            r.w = acc[i][3] + bb.w;
            if (RELU) {
                r.x = fmaxf(r.x, 0.f); r.y = fmaxf(r.y, 0.f);
                r.z = fmaxf(r.z, 0.f); r.w = fmaxf(r.w, 0.f);
            }
            *(float4*)(out + (size_t)node * 64 + tn * 4) = r;
        }
    }
}

// ---------------- pooling ----------------

__global__ void k_bounds(const int* __restrict__ batch, int* __restrict__ gstart,
                         int* __restrict__ gend, int n) {
    int i = blockIdx.x * blockDim.x + threadIdx.x;
    if (i < n) {
        int b = batch[i];
        if (i == 0 || batch[i - 1] != b) gstart[b] = i;
        if (i == n - 1 || batch[i + 1] != b) gend[b] = i + 1;
    }
}

__global__ void k_pool(const float* __restrict__ h, const int* __restrict__ gstart,
                       const int* __restrict__ gend, const float* __restrict__ T,
                       float* __restrict__ pool) {
    int g = blockIdx.x;
    int l = threadIdx.x;  // 64 threads
    int s0 = gstart[g], s1 = gend[g];
    float s0a = 0.f, s1a = 0.f, s2a = 0.f, s3a = 0.f;
    float m0 = -INFINITY, m1 = -INFINITY, m2 = -INFINITY, m3 = -INFINITY;
    int n = s0;
    for (; n + 4 <= s1; n += 4) {
        float v0 = h[(size_t)n * 64 + l];
        float v1 = h[(size_t)(n + 1) * 64 + l];
        float v2 = h[(size_t)(n + 2) * 64 + l];
        float v3 = h[(size_t)(n + 3) * 64 + l];
        s0a += v0; s1a += v1; s2a += v2; s3a += v3;
        m0 = fmaxf(m0, v0); m1 = fmaxf(m1, v1);
        m2 = fmaxf(m2, v2); m3 = fmaxf(m3, v3);
    }
    for (; n < s1; n++) {
        float v = h[(size_t)n * 64 + l];
        s0a += v;
        m0 = fmaxf(m0, v);
    }
    float s = (s0a + s1a) + (s2a + s3a);
    float mx = fmaxf(fmaxf(m0, m1), fmaxf(m2, m3));
    int cnt = s1 - s0;
    float mean = s / fmaxf((float)cnt, 1.f);
    if (cnt == 0) mx = 0.f;
    float* row = pool + (size_t)g * 193;
    row[l] = mx;
    row[64 + l] = mean;
    row[128 + l] = s;
    if (l == 0) row[192] = T[g];
}

// ---------------- MLP head ----------------

__global__ __launch_bounds__(256) void k_mlp(
    const float* __restrict__ pool, const float* __restrict__ w1,
    const float* __restrict__ b1, const float* __restrict__ w2,
    const float* __restrict__ b2, const float* __restrict__ w3,
    const float* __restrict__ b3, float* __restrict__ out) {
    __shared__ float sin_[193];
    __shared__ float so1[256];
    __shared__ float red[256];
    int g = blockIdx.x, t = threadIdx.x;
    if (t < 193) sin_[t] = pool[(size_t)g * 193 + t];
    __syncthreads();
    float a = b1[t];
    for (int k = 0; k < 193; k++) a += sin_[k] * w1[k * 256 + t];
    a = fmaxf(a, 0.f);
    so1[t] = a;
    __syncthreads();
    float a2 = b2[t];
    for (int k = 0; k < 256; k++) a2 += so1[k] * w2[k * 256 + t];
    a2 = fmaxf(a2, 0.f);
    red[t] = a2 * w3[t];
    __syncthreads();
    for (int s = 128; s > 0; s >>= 1) {
        if (t < s) red[t] += red[t + s];
        __syncthreads();
    }
    if (t == 0) out[g] = red[0] + b3[0];
}

extern "C" void kernel_launch(void* const* d_in, const int* in_sizes, int n_in,
                              void* d_out, int out_size, void* d_ws, size_t ws_size,
                              hipStream_t stream) {
    const int N = N_NODES, E = N_EDGES, G = N_GRAPHS;

    const float* x = (const float*)d_in[0];
    const int* ei = (const int*)d_in[1];
    const int* batch = (const int*)d_in[2];
    const float* T = (const float*)d_in[3];
    const float* wrel[4] = {(const float*)d_in[4], (const float*)d_in[7],
                            (const float*)d_in[10], (const float*)d_in[13]};
    const float* brel[4] = {(const float*)d_in[5], (const float*)d_in[8],
                            (const float*)d_in[11], (const float*)d_in[14]};
    const float* wroot[4] = {(const float*)d_in[6], (const float*)d_in[9],
                             (const float*)d_in[12], (const float*)d_in[15]};
    const float* w1 = (const float*)d_in[16];
    const float* b1 = (const float*)d_in[17];
    const float* w2 = (const float*)d_in[18];
    const float* b2 = (const float*)d_in[19];
    const float* w3 = (const float*)d_in[20];
    const float* b3 = (const float*)d_in[21];
    float* out = (float*)d_out;

    const int* esrc = ei;
    const int* edst = ei + E;

    // workspace layout
    char* ws = (char*)d_ws;
    size_t off = 0;
    auto alloc = [&](size_t bytes) {
        size_t r = off;
        off = (off + bytes + 255) & ~(size_t)255;
        return r;
    };
    int* cnt = (int*)(ws + alloc((size_t)N * 4));
    int* rowptr = (int*)(ws + alloc((size_t)(N + 1) * 4));
    int* cursor = (int*)(ws + alloc((size_t)N * 4));
    int* bsum = (int*)(ws + alloc(512));
    int* ssrc = (int*)(ws + alloc((size_t)E * 4));
    float* h0 = (float*)(ws + alloc((size_t)N * 64 * 4));
    float* h1 = (float*)(ws + alloc((size_t)N * 64 * 4));
    float* agg = (float*)(ws + alloc((size_t)N * 64 * 4));
    int* gstart = (int*)(ws + alloc((size_t)G * 4));
    int* gend = (int*)(ws + alloc((size_t)G * 4));
    float* pool = (float*)(ws + alloc((size_t)G * 193 * 4));

    // 1. CSR build
    hipMemsetAsync(cnt, 0, (size_t)N * 4, stream);
    hipMemsetAsync(gstart, 0, (size_t)G * 4, stream);
    hipMemsetAsync(gend, 0, (size_t)G * 4, stream);
    k_hist<<<(E + 255) / 256, 256, 0, stream>>>(edst, cnt, E);
    int nb1 = (N + 1023) / 1024;
    k_scan1<<<nb1, 256, 0, stream>>>(cnt, rowptr, bsum, N);
    k_scan2<<<1, 128, 0, stream>>>(bsum, nb1);
    k_scan3<<<(N + 255) / 256, 256, 0, stream>>>(rowptr, cursor, bsum, N, E);
    k_scatter<<<(E + 255) / 256, 256, 0, stream>>>(esrc, edst, cursor, ssrc, E);

    // 2. four conv layers = (agg, dense) pairs, ping-pong h buffers
    int agg_blocks = (N * 64 + 255) / 256;   // one wave per node
    int gemm_blocks = (N + 63) / 64;         // 64-node tile per block

    k_agg<<<agg_blocks, 256, 0, stream>>>(x, agg, rowptr, ssrc, N);
    k_gemm<1><<<gemm_blocks, 256, 0, stream>>>(x, agg, wroot[0], wrel[0], brel[0], h0, N);

    k_agg<<<agg_blocks, 256, 0, stream>>>(h0, agg, rowptr, ssrc, N);
    k_gemm<1><<<gemm_blocks, 256, 0, stream>>>(h0, agg, wroot[1], wrel[1], brel[1], h1, N);

    k_agg<<<agg_blocks, 256, 0, stream>>>(h1, agg, rowptr, ssrc, N);
    k_gemm<1><<<gemm_blocks, 256, 0, stream>>>(h1, agg, wroot[2], wrel[2], brel[2], h0, N);

    k_agg<<<agg_blocks, 256, 0, stream>>>(h0, agg, rowptr, ssrc, N);
    k_gemm<0><<<gemm_blocks, 256, 0, stream>>>(h0, agg, wroot[3], wrel[3], brel[3], h1, N);

    // 3. pooling
    k_bounds<<<(N + 255) / 256, 256, 0, stream>>>(batch, gstart, gend, N);
    k_pool<<<G, 64, 0, stream>>>(h1, gstart, gend, T, pool);

    // 4. MLP head
    k_mlp<<<G, 256, 0, stream>>>(pool, w1, b1, w2, b2, w3, b3, out);
}

// Round 4
// 768.883 us; speedup vs baseline: 2.8849x; 1.0081x over previous
//
#include <hip/hip_runtime.h>
#include <hip/hip_bf16.h>
#include <math.h>

#define N_NODES 100000
#define N_EDGES 1600000
#define N_FEAT 64
#define HID 64
#define HL 256
#define N_GRAPHS 512

#define BUCKET_BITS 7
#define BUCKET_SIZE 128
#define NB ((N_NODES + BUCKET_SIZE - 1) / BUCKET_SIZE)   // 782
#define EDGES_PER_BLOCK 4096

// bf16 helpers (manual RNE; values are finite)
__device__ __forceinline__ unsigned short f2b(float f) {
    unsigned int u = __float_as_uint(f);
    return (unsigned short)((u + 0x7FFFu + ((u >> 16) & 1u)) >> 16);
}
__device__ __forceinline__ float b2f(unsigned short u) {
    return __uint_as_float(((unsigned int)u) << 16);
}

// ---------------- CSR build (bucketed, write-amplification-free) ----------

// node histogram (global atomics) + bucket histogram (LDS, flushed once)
__global__ __launch_bounds__(256) void k_hist(const int* __restrict__ dst,
        int* __restrict__ cnt, int* __restrict__ bcnt, int e) {
    __shared__ int lh[NB];
    for (int t = threadIdx.x; t < NB; t += 256) lh[t] = 0;
    __syncthreads();
    int stride = gridDim.x * 256;
    for (int i = blockIdx.x * 256 + threadIdx.x; i < e; i += stride) {
        int d = dst[i];
        atomicAdd(&cnt[d], 1);
        atomicAdd(&lh[d >> BUCKET_BITS], 1);
    }
    __syncthreads();
    for (int t = threadIdx.x; t < NB; t += 256)
        if (lh[t]) atomicAdd(&bcnt[t], lh[t]);
}

// exclusive scan of NB bucket counts (single 1024-thread block)
__global__ void k_bscan(const int* __restrict__ bcnt, int* __restrict__ boff,
                        int* __restrict__ bcur, int e) {
    __shared__ int sdata[1024];
    int t = threadIdx.x;
    int v = (t < NB) ? bcnt[t] : 0;
    sdata[t] = v;
    __syncthreads();
    for (int off = 1; off < 1024; off <<= 1) {
        int x = sdata[t];
        int y = (t >= off) ? sdata[t - off] : 0;
        __syncthreads();
        sdata[t] = x + y;
        __syncthreads();
    }
    if (t < NB) {
        int ex = sdata[t] - v;
        boff[t] = ex;
        bcur[t] = ex;
    }
    if (t == 0) boff[NB] = e;
}

// scatter (src,dst) records into bucket-ordered ebuf; per-block LDS claim
// makes each block's writes per bucket a contiguous run (dense lines).
__global__ __launch_bounds__(256) void k_bscatter(const int* __restrict__ src,
        const int* __restrict__ dst, int* __restrict__ bcur,
        int2* __restrict__ ebuf, int e) {
    __shared__ int lh[NB];
    __shared__ int lbase[NB];
    for (int t = threadIdx.x; t < NB; t += 256) lh[t] = 0;
    __syncthreads();
    int i0 = blockIdx.x * EDGES_PER_BLOCK;
    int i1 = min(e, i0 + EDGES_PER_BLOCK);
    for (int i = i0 + threadIdx.x; i < i1; i += 256)
        atomicAdd(&lh[dst[i] >> BUCKET_BITS], 1);
    __syncthreads();
    for (int t = threadIdx.x; t < NB; t += 256) {
        int c = lh[t];
        lbase[t] = c ? atomicAdd(&bcur[t], c) : 0;
        lh[t] = 0;  // reuse as local cursor
    }
    __syncthreads();
    for (int i = i0 + threadIdx.x; i < i1; i += 256) {
        int s = src[i], d = dst[i];
        int b = d >> BUCKET_BITS;
        int p = lbase[b] + atomicAdd(&lh[b], 1);
        ebuf[p] = make_int2(s, d);
    }
}

// per-bucket final scatter: LDS cursors, writes confined to ~8KB region
__global__ __launch_bounds__(256) void k_fscatter(const int2* __restrict__ ebuf,
        const int* __restrict__ boff, const int* __restrict__ rowptr,
        int* __restrict__ ssrc, int n) {
    __shared__ int cur[BUCKET_SIZE];
    int b = blockIdx.x;
    int n0 = b * BUCKET_SIZE;
    int t = threadIdx.x;
    if (t < BUCKET_SIZE && n0 + t < n) cur[t] = rowptr[n0 + t];
    __syncthreads();
    int r0 = boff[b], r1 = boff[b + 1];
    for (int r = r0 + t; r < r1; r += 256) {
        int2 e = ebuf[r];
        int p = atomicAdd(&cur[e.y - n0], 1);
        ssrc[p] = e.x;
    }
}

// node-count exclusive scan (1024 per block, 3 kernels)
__global__ void k_scan1(const int* __restrict__ cnt, int* __restrict__ rowptr,
                        int* __restrict__ bsum, int n) {
    __shared__ int sdata[256];
    int t = threadIdx.x;
    int base = blockIdx.x * 1024 + t * 4;
    int v[4];
    int s = 0;
#pragma unroll
    for (int j = 0; j < 4; j++) {
        int idx = base + j;
        v[j] = (idx < n) ? cnt[idx] : 0;
        s += v[j];
    }
    sdata[t] = s;
    __syncthreads();
    for (int off = 1; off < 256; off <<= 1) {
        int x = sdata[t];
        int y = (t >= off) ? sdata[t - off] : 0;
        __syncthreads();
        sdata[t] = x + y;
        __syncthreads();
    }
    int incl = sdata[t];
    int excl = incl - s;
    if (t == 255) bsum[blockIdx.x] = incl;
    int run = excl;
#pragma unroll
    for (int j = 0; j < 4; j++) {
        int idx = base + j;
        if (idx < n) rowptr[idx] = run;
        run += v[j];
    }
}

__global__ void k_scan2(int* __restrict__ bsum, int nb) {
    __shared__ int sdata[128];
    int t = threadIdx.x;
    int v = (t < nb) ? bsum[t] : 0;
    sdata[t] = v;
    __syncthreads();
    for (int off = 1; off < 128; off <<= 1) {
        int x = sdata[t];
        int y = (t >= off) ? sdata[t - off] : 0;
        __syncthreads();
        sdata[t] = x + y;
        __syncthreads();
    }
    if (t < nb) bsum[t] = sdata[t] - v;  // exclusive
}

__global__ void k_scan3(int* __restrict__ rowptr, const int* __restrict__ bsum,
                        int n, int e) {
    int i = blockIdx.x * blockDim.x + threadIdx.x;
    if (i == 0) rowptr[n] = e;
    if (i < n) rowptr[i] += bsum[i >> 10];
}

// ---------------- fp32 -> bf16 convert (layer-0 input) ----------------

__global__ __launch_bounds__(256) void k_f2b(const float4* __restrict__ x,
        ushort4* __restrict__ xb, int nq) {
    int i = blockIdx.x * 256 + threadIdx.x;
    if (i < nq) {
        float4 v = x[i];
        ushort4 o;
        o.x = f2b(v.x); o.y = f2b(v.y); o.z = f2b(v.z); o.w = f2b(v.w);
        xb[i] = o;
    }
}

// ---------------- aggregation: agg[i] = sum_{j->i} h[j] (bf16 in) ----------

__global__ __launch_bounds__(256) void k_agg(
    const unsigned short* __restrict__ hb, float* __restrict__ agg,
    const int* __restrict__ rowptr, const int* __restrict__ ssrc, int n) {
    int lane = threadIdx.x & 63;
    int i = (blockIdx.x * 256 + threadIdx.x) >> 6;
    if (i >= n) return;
    int e0 = rowptr[i], e1 = rowptr[i + 1];
    float a0 = 0.f, a1 = 0.f, a2 = 0.f, a3 = 0.f;
    int e = e0;
    for (; e + 4 <= e1; e += 4) {
        int j0 = ssrc[e], j1 = ssrc[e + 1], j2 = ssrc[e + 2], j3 = ssrc[e + 3];
        a0 += b2f(hb[(size_t)j0 * 64 + lane]);
        a1 += b2f(hb[(size_t)j1 * 64 + lane]);
        a2 += b2f(hb[(size_t)j2 * 64 + lane]);
        a3 += b2f(hb[(size_t)j3 * 64 + lane]);
    }
    for (; e < e1; e++) a0 += b2f(hb[(size_t)ssrc[e] * 64 + lane]);
    agg[(size_t)i * 64 + lane] = (a0 + a1) + (a2 + a3);
}

// ---------------- dense fused: hbout = [relu](h@wroot + agg@wrel + b) ------
// LDS-staged register-tiled GEMM; h in bf16, agg fp32, compute fp32.

#define SX_LD 68

template <int RELU>
__global__ __launch_bounds__(256) void k_gemm(
    const unsigned short* __restrict__ hb, const float* __restrict__ agg,
    const float* __restrict__ wroot, const float* __restrict__ wrel,
    const float* __restrict__ brel, unsigned short* __restrict__ hbout, int n) {
    __shared__ float sw[128 * 64];   // rows 0-63: wroot, 64-127: wrel
    __shared__ float sx[64 * SX_LD];

    int tid = threadIdx.x;
    int tm = tid >> 4;
    int tn = tid & 15;
    int m0 = blockIdx.x * 64;

    {
        const float4* a = (const float4*)wroot;
        const float4* b = (const float4*)wrel;
        float4* s = (float4*)sw;
#pragma unroll
        for (int r = 0; r < 4; r++) s[tid + 256 * r] = a[tid + 256 * r];
#pragma unroll
        for (int r = 0; r < 4; r++) s[1024 + tid + 256 * r] = b[tid + 256 * r];
    }

    float acc[4][4];
#pragma unroll
    for (int i = 0; i < 4; i++)
#pragma unroll
        for (int j = 0; j < 4; j++) acc[i][j] = 0.f;

    for (int phase = 0; phase < 2; phase++) {
        __syncthreads();
        if (phase == 0) {
#pragma unroll
            for (int r = 0; r < 4; r++) {
                int f = tid + 256 * r;
                int node = f >> 4, kc = f & 15;
                int gnode = m0 + node;
                float4 v = make_float4(0.f, 0.f, 0.f, 0.f);
                if (gnode < n) {
                    ushort4 u = ((const ushort4*)(hb + (size_t)gnode * 64))[kc];
                    v.x = b2f(u.x); v.y = b2f(u.y); v.z = b2f(u.z); v.w = b2f(u.w);
                }
                *(float4*)(sx + node * SX_LD + kc * 4) = v;
            }
        } else {
#pragma unroll
            for (int r = 0; r < 4; r++) {
                int f = tid + 256 * r;
                int node = f >> 4, kc = f & 15;
                int gnode = m0 + node;
                float4 v = make_float4(0.f, 0.f, 0.f, 0.f);
                if (gnode < n) v = ((const float4*)(agg + (size_t)gnode * 64))[kc];
                *(float4*)(sx + node * SX_LD + kc * 4) = v;
            }
        }
        __syncthreads();

        const float* wbase = sw + phase * 64 * 64;
#pragma unroll
        for (int kc = 0; kc < 16; kc++) {
            float4 xv[4], wv[4];
#pragma unroll
            for (int i = 0; i < 4; i++)
                xv[i] = *(const float4*)(sx + (tm * 4 + i) * SX_LD + kc * 4);
#pragma unroll
            for (int kk = 0; kk < 4; kk++)
                wv[kk] = *(const float4*)(wbase + (kc * 4 + kk) * 64 + tn * 4);
#pragma unroll
            for (int i = 0; i < 4; i++) {
                float xs0 = xv[i].x, xs1 = xv[i].y, xs2 = xv[i].z, xs3 = xv[i].w;
                acc[i][0] += xs0 * wv[0].x + xs1 * wv[1].x + xs2 * wv[2].x + xs3 * wv[3].x;
                acc[i][1] += xs0 * wv[0].y + xs1 * wv[1].y + xs2 * wv[2].y + xs3 * wv[3].y;
                acc[i][2] += xs0 * wv[0].z + xs1 * wv[1].z + xs2 * wv[2].z + xs3 * wv[3].z;
                acc[i][3] += xs0 * wv[0].w + xs1 * wv[1].w + xs2 * wv[2].w + xs3 * wv[3].w;
            }
        }
    }

    float4 bb = *(const float4*)(brel + tn * 4);
#pragma unroll
    for (int i = 0; i < 4; i++) {
        int node = m0 + tm * 4 + i;
        if (node < n) {
            float4 r;
            r.x = acc[i][0] + bb.x;
            r.y = acc[i][1] + bb.y;
            r.z = acc[i][2] + bb.z;
            r.w = acc[i][3] + bb.w;
            if (RELU) {
                r.x = fmaxf(r.x, 0.f); r.y = fmaxf(r.y, 0.f);
                r.z = fmaxf(r.z, 0.f); r.w = fmaxf(r.w, 0.f);
            }
            ushort4 o;
            o.x = f2b(r.x); o.y = f2b(r.y); o.z = f2b(r.z); o.w = f2b(r.w);
            *(ushort4*)(hbout + (size_t)node * 64 + tn * 4) = o;
        }
    }
}

// ---------------- pooling ----------------

__global__ void k_bounds(const int* __restrict__ batch, int* __restrict__ gstart,
                         int* __restrict__ gend, int n) {
    int i = blockIdx.x * blockDim.x + threadIdx.x;
    if (i < n) {
        int b = batch[i];
        if (i == 0 || batch[i - 1] != b) gstart[b] = i;
        if (i == n - 1 || batch[i + 1] != b) gend[b] = i + 1;
    }
}

__global__ void k_pool(const unsigned short* __restrict__ hb,
                       const int* __restrict__ gstart,
                       const int* __restrict__ gend, const float* __restrict__ T,
                       float* __restrict__ pool) {
    int g = blockIdx.x;
    int l = threadIdx.x;  // 64 threads
    int s0 = gstart[g], s1 = gend[g];
    float s0a = 0.f, s1a = 0.f, s2a = 0.f, s3a = 0.f;
    float m0 = -INFINITY, m1 = -INFINITY, m2 = -INFINITY, m3 = -INFINITY;
    int n = s0;
    for (; n + 4 <= s1; n += 4) {
        float v0 = b2f(hb[(size_t)n * 64 + l]);
        float v1 = b2f(hb[(size_t)(n + 1) * 64 + l]);
        float v2 = b2f(hb[(size_t)(n + 2) * 64 + l]);
        float v3 = b2f(hb[(size_t)(n + 3) * 64 + l]);
        s0a += v0; s1a += v1; s2a += v2; s3a += v3;
        m0 = fmaxf(m0, v0); m1 = fmaxf(m1, v1);
        m2 = fmaxf(m2, v2); m3 = fmaxf(m3, v3);
    }
    for (; n < s1; n++) {
        float v = b2f(hb[(size_t)n * 64 + l]);
        s0a += v;
        m0 = fmaxf(m0, v);
    }
    float s = (s0a + s1a) + (s2a + s3a);
    float mx = fmaxf(fmaxf(m0, m1), fmaxf(m2, m3));
    int cnt = s1 - s0;
    float mean = s / fmaxf((float)cnt, 1.f);
    if (cnt == 0) mx = 0.f;
    float* row = pool + (size_t)g * 193;
    row[l] = mx;
    row[64 + l] = mean;
    row[128 + l] = s;
    if (l == 0) row[192] = T[g];
}

// ---------------- MLP head ----------------

__global__ __launch_bounds__(256) void k_mlp(
    const float* __restrict__ pool, const float* __restrict__ w1,
    const float* __restrict__ b1, const float* __restrict__ w2,
    const float* __restrict__ b2, const float* __restrict__ w3,
    const float* __restrict__ b3, float* __restrict__ out) {
    __shared__ float sin_[193];
    __shared__ float so1[256];
    __shared__ float red[256];
    int g = blockIdx.x, t = threadIdx.x;
    if (t < 193) sin_[t] = pool[(size_t)g * 193 + t];
    __syncthreads();
    float a = b1[t];
    for (int k = 0; k < 193; k++) a += sin_[k] * w1[k * 256 + t];
    a = fmaxf(a, 0.f);
    so1[t] = a;
    __syncthreads();
    float a2 = b2[t];
    for (int k = 0; k < 256; k++) a2 += so1[k] * w2[k * 256 + t];
    a2 = fmaxf(a2, 0.f);
    red[t] = a2 * w3[t];
    __syncthreads();
    for (int s = 128; s > 0; s >>= 1) {
        if (t < s) red[t] += red[t + s];
        __syncthreads();
    }
    if (t == 0) out[g] = red[0] + b3[0];
}

extern "C" void kernel_launch(void* const* d_in, const int* in_sizes, int n_in,
                              void* d_out, int out_size, void* d_ws, size_t ws_size,
                              hipStream_t stream) {
    const int N = N_NODES, E = N_EDGES, G = N_GRAPHS;

    const float* x = (const float*)d_in[0];
    const int* ei = (const int*)d_in[1];
    const int* batch = (const int*)d_in[2];
    const float* T = (const float*)d_in[3];
    const float* wrel[4] = {(const float*)d_in[4], (const float*)d_in[7],
                            (const float*)d_in[10], (const float*)d_in[13]};
    const float* brel[4] = {(const float*)d_in[5], (const float*)d_in[8],
                            (const float*)d_in[11], (const float*)d_in[14]};
    const float* wroot[4] = {(const float*)d_in[6], (const float*)d_in[9],
                             (const float*)d_in[12], (const float*)d_in[15]};
    const float* w1 = (const float*)d_in[16];
    const float* b1 = (const float*)d_in[17];
    const float* w2 = (const float*)d_in[18];
    const float* b2 = (const float*)d_in[19];
    const float* w3 = (const float*)d_in[20];
    const float* b3 = (const float*)d_in[21];
    float* out = (float*)d_out;

    const int* esrc = ei;
    const int* edst = ei + E;

    // workspace layout (~71 MB)
    char* ws = (char*)d_ws;
    size_t off = 0;
    auto alloc = [&](size_t bytes) {
        size_t r = off;
        off = (off + bytes + 255) & ~(size_t)255;
        return r;
    };
    int* cnt = (int*)(ws + alloc((size_t)N * 4));
    int* rowptr = (int*)(ws + alloc((size_t)(N + 1) * 4));
    int* bsum = (int*)(ws + alloc(512));
    int* bcnt = (int*)(ws + alloc((size_t)NB * 4));
    int* boff = (int*)(ws + alloc((size_t)(NB + 1) * 4));
    int* bcur = (int*)(ws + alloc((size_t)NB * 4));
    int* ssrc = (int*)(ws + alloc((size_t)E * 4));
    int2* ebuf = (int2*)(ws + alloc((size_t)E * 8));
    unsigned short* hbA = (unsigned short*)(ws + alloc((size_t)N * 64 * 2));
    unsigned short* hbB = (unsigned short*)(ws + alloc((size_t)N * 64 * 2));
    float* agg = (float*)(ws + alloc((size_t)N * 64 * 4));
    int* gstart = (int*)(ws + alloc((size_t)G * 4));
    int* gend = (int*)(ws + alloc((size_t)G * 4));
    float* pool = (float*)(ws + alloc((size_t)G * 193 * 4));

    // 1. CSR build (bucketed)
    hipMemsetAsync(cnt, 0, (size_t)N * 4, stream);
    hipMemsetAsync(bcnt, 0, (size_t)NB * 4, stream);
    hipMemsetAsync(gstart, 0, (size_t)G * 4, stream);
    hipMemsetAsync(gend, 0, (size_t)G * 4, stream);
    int hist_blocks = (E + EDGES_PER_BLOCK - 1) / EDGES_PER_BLOCK;  // 391
    k_hist<<<hist_blocks, 256, 0, stream>>>(edst, cnt, bcnt, E);
    k_bscan<<<1, 1024, 0, stream>>>(bcnt, boff, bcur, E);
    int nb1 = (N + 1023) / 1024;
    k_scan1<<<nb1, 256, 0, stream>>>(cnt, rowptr, bsum, N);
    k_scan2<<<1, 128, 0, stream>>>(bsum, nb1);
    k_scan3<<<(N + 255) / 256, 256, 0, stream>>>(rowptr, bsum, N, E);
    k_bscatter<<<hist_blocks, 256, 0, stream>>>(esrc, edst, bcur, ebuf, E);
    k_fscatter<<<NB, 256, 0, stream>>>(ebuf, boff, rowptr, ssrc, N);

    // 2. convert input to bf16
    int nq = N * 64 / 4;
    k_f2b<<<(nq + 255) / 256, 256, 0, stream>>>((const float4*)x, (ushort4*)hbA, nq);

    // 3. four conv layers (bf16 h ping-pong)
    int agg_blocks = (N * 64 + 255) / 256;   // one wave per node
    int gemm_blocks = (N + 63) / 64;         // 64-node tile per block

    k_agg<<<agg_blocks, 256, 0, stream>>>(hbA, agg, rowptr, ssrc, N);
    k_gemm<1><<<gemm_blocks, 256, 0, stream>>>(hbA, agg, wroot[0], wrel[0], brel[0], hbB, N);

    k_agg<<<agg_blocks, 256, 0, stream>>>(hbB, agg, rowptr, ssrc, N);
    k_gemm<1><<<gemm_blocks, 256, 0, stream>>>(hbB, agg, wroot[1], wrel[1], brel[1], hbA, N);

    k_agg<<<agg_blocks, 256, 0, stream>>>(hbA, agg, rowptr, ssrc, N);
    k_gemm<1><<<gemm_blocks, 256, 0, stream>>>(hbA, agg, wroot[2], wrel[2], brel[2], hbB, N);

    k_agg<<<agg_blocks, 256, 0, stream>>>(hbB, agg, rowptr, ssrc, N);
    k_gemm<0><<<gemm_blocks, 256, 0, stream>>>(hbB, agg, wroot[3], wrel[3], brel[3], hbA, N);

    // 4. pooling
    k_bounds<<<(N + 255) / 256, 256, 0, stream>>>(batch, gstart, gend, N);
    k_pool<<<G, 64, 0, stream>>>(hbA, gstart, gend, T, pool);

    // 5. MLP head
    k_mlp<<<G, 256, 0, stream>>>(pool, w1, b1, w2, b2, w3, b3, out);
}

// Round 5
// 614.611 us; speedup vs baseline: 3.6091x; 1.2510x over previous
//
#include <hip/hip_runtime.h>
#include <hip/hip_bf16.h>
#include <math.h>

#define N_NODES 100000
#define N_EDGES 1600000
#define N_FEAT 64
#define HID 64
#define HL 256
#define N_GRAPHS 512

#define BUCKET_BITS 7
#define BUCKET_SIZE 128
#define NB ((N_NODES + BUCKET_SIZE - 1) / BUCKET_SIZE)   // 782
#define EDGES_PER_BLOCK 4096

typedef short vbf8 __attribute__((ext_vector_type(8)));
typedef float vf4 __attribute__((ext_vector_type(4)));

// bf16 helpers (manual RNE; values are finite)
__device__ __forceinline__ unsigned short f2b(float f) {
    unsigned int u = __float_as_uint(f);
    return (unsigned short)((u + 0x7FFFu + ((u >> 16) & 1u)) >> 16);
}
__device__ __forceinline__ float b2f(unsigned short u) {
    return __uint_as_float(((unsigned int)u) << 16);
}

// ---------------- CSR build (bucketed, write-amplification-free) ----------

__global__ __launch_bounds__(256) void k_hist(const int* __restrict__ dst,
        int* __restrict__ cnt, int* __restrict__ bcnt, int e) {
    __shared__ int lh[NB];
    for (int t = threadIdx.x; t < NB; t += 256) lh[t] = 0;
    __syncthreads();
    int stride = gridDim.x * 256;
    for (int i = blockIdx.x * 256 + threadIdx.x; i < e; i += stride) {
        int d = dst[i];
        atomicAdd(&cnt[d], 1);
        atomicAdd(&lh[d >> BUCKET_BITS], 1);
    }
    __syncthreads();
    for (int t = threadIdx.x; t < NB; t += 256)
        if (lh[t]) atomicAdd(&bcnt[t], lh[t]);
}

__global__ void k_bscan(const int* __restrict__ bcnt, int* __restrict__ boff,
                        int* __restrict__ bcur, int e) {
    __shared__ int sdata[1024];
    int t = threadIdx.x;
    int v = (t < NB) ? bcnt[t] : 0;
    sdata[t] = v;
    __syncthreads();
    for (int off = 1; off < 1024; off <<= 1) {
        int x = sdata[t];
        int y = (t >= off) ? sdata[t - off] : 0;
        __syncthreads();
        sdata[t] = x + y;
        __syncthreads();
    }
    if (t < NB) {
        int ex = sdata[t] - v;
        boff[t] = ex;
        bcur[t] = ex;
    }
    if (t == 0) boff[NB] = e;
}

__global__ __launch_bounds__(256) void k_bscatter(const int* __restrict__ src,
        const int* __restrict__ dst, int* __restrict__ bcur,
        int2* __restrict__ ebuf, int e) {
    __shared__ int lh[NB];
    __shared__ int lbase[NB];
    for (int t = threadIdx.x; t < NB; t += 256) lh[t] = 0;
    __syncthreads();
    int i0 = blockIdx.x * EDGES_PER_BLOCK;
    int i1 = min(e, i0 + EDGES_PER_BLOCK);
    for (int i = i0 + threadIdx.x; i < i1; i += 256)
        atomicAdd(&lh[dst[i] >> BUCKET_BITS], 1);
    __syncthreads();
    for (int t = threadIdx.x; t < NB; t += 256) {
        int c = lh[t];
        lbase[t] = c ? atomicAdd(&bcur[t], c) : 0;
        lh[t] = 0;  // reuse as local cursor
    }
    __syncthreads();
    for (int i = i0 + threadIdx.x; i < i1; i += 256) {
        int s = src[i], d = dst[i];
        int b = d >> BUCKET_BITS;
        int p = lbase[b] + atomicAdd(&lh[b], 1);
        ebuf[p] = make_int2(s, d);
    }
}

__global__ __launch_bounds__(256) void k_fscatter(const int2* __restrict__ ebuf,
        const int* __restrict__ boff, const int* __restrict__ rowptr,
        int* __restrict__ ssrc, int n) {
    __shared__ int cur[BUCKET_SIZE];
    int b = blockIdx.x;
    int n0 = b * BUCKET_SIZE;
    int t = threadIdx.x;
    if (t < BUCKET_SIZE && n0 + t < n) cur[t] = rowptr[n0 + t];
    __syncthreads();
    int r0 = boff[b], r1 = boff[b + 1];
    for (int r = r0 + t; r < r1; r += 256) {
        int2 e = ebuf[r];
        int p = atomicAdd(&cur[e.y - n0], 1);
        ssrc[p] = e.x;
    }
}

__global__ void k_scan1(const int* __restrict__ cnt, int* __restrict__ rowptr,
                        int* __restrict__ bsum, int n) {
    __shared__ int sdata[256];
    int t = threadIdx.x;
    int base = blockIdx.x * 1024 + t * 4;
    int v[4];
    int s = 0;
#pragma unroll
    for (int j = 0; j < 4; j++) {
        int idx = base + j;
        v[j] = (idx < n) ? cnt[idx] : 0;
        s += v[j];
    }
    sdata[t] = s;
    __syncthreads();
    for (int off = 1; off < 256; off <<= 1) {
        int x = sdata[t];
        int y = (t >= off) ? sdata[t - off] : 0;
        __syncthreads();
        sdata[t] = x + y;
        __syncthreads();
    }
    int incl = sdata[t];
    int excl = incl - s;
    if (t == 255) bsum[blockIdx.x] = incl;
    int run = excl;
#pragma unroll
    for (int j = 0; j < 4; j++) {
        int idx = base + j;
        if (idx < n) rowptr[idx] = run;
        run += v[j];
    }
}

__global__ void k_scan2(int* __restrict__ bsum, int nb) {
    __shared__ int sdata[128];
    int t = threadIdx.x;
    int v = (t < nb) ? bsum[t] : 0;
    sdata[t] = v;
    __syncthreads();
    for (int off = 1; off < 128; off <<= 1) {
        int x = sdata[t];
        int y = (t >= off) ? sdata[t - off] : 0;
        __syncthreads();
        sdata[t] = x + y;
        __syncthreads();
    }
    if (t < nb) bsum[t] = sdata[t] - v;  // exclusive
}

__global__ void k_scan3(int* __restrict__ rowptr, const int* __restrict__ bsum,
                        int n, int e) {
    int i = blockIdx.x * blockDim.x + threadIdx.x;
    if (i == 0) rowptr[n] = e;
    if (i < n) rowptr[i] += bsum[i >> 10];
}

// ---------------- fp32 -> bf16 convert (layer-0 input) ----------------

__global__ __launch_bounds__(256) void k_f2b(const float4* __restrict__ x,
        ushort4* __restrict__ xb, int nq) {
    int i = blockIdx.x * 256 + threadIdx.x;
    if (i < nq) {
        float4 v = x[i];
        ushort4 o;
        o.x = f2b(v.x); o.y = f2b(v.y); o.z = f2b(v.z); o.w = f2b(v.w);
        xb[i] = o;
    }
}

// ---------------- weight prep: Wt[n][k] bf16, k = [wroot 0..63 | wrel 64..127]

__global__ __launch_bounds__(256) void k_wprep(const float* __restrict__ wroot,
        const float* __restrict__ wrel, unsigned short* __restrict__ wt) {
    int i = blockIdx.x * 256 + threadIdx.x;   // 0..8191
    if (i >= 64 * 128) return;
    int nn = i >> 7, k = i & 127;
    float v = (k < 64) ? wroot[k * 64 + nn] : wrel[(k - 64) * 64 + nn];
    wt[i] = f2b(v);
}

// ---------------- aggregation: aggb[i] = sum_{j->i} h[j] (bf16 in/out) -----

__global__ __launch_bounds__(256) void k_agg(
    const unsigned short* __restrict__ hb, unsigned short* __restrict__ aggb,
    const int* __restrict__ rowptr, const int* __restrict__ ssrc, int n) {
    int lane = threadIdx.x & 63;
    int i = (blockIdx.x * 256 + threadIdx.x) >> 6;
    if (i >= n) return;
    int e0 = rowptr[i], e1 = rowptr[i + 1];
    float a[8] = {0.f, 0.f, 0.f, 0.f, 0.f, 0.f, 0.f, 0.f};
    int e = e0;
    for (; e + 8 <= e1; e += 8) {
#pragma unroll
        for (int u = 0; u < 8; u++) {
            int j = ssrc[e + u];
            a[u] += b2f(hb[(size_t)j * 64 + lane]);
        }
    }
    for (; e < e1; e++) a[0] += b2f(hb[(size_t)ssrc[e] * 64 + lane]);
    float s = ((a[0] + a[1]) + (a[2] + a[3])) + ((a[4] + a[5]) + (a[6] + a[7]));
    aggb[(size_t)i * 64 + lane] = f2b(s);
}

// ---------------- MFMA gemm: hbout = [relu]([hb|aggb] @ Wt^T + brel) -------
// Block = 64 nodes = 4 waves x 16 rows. A/B frags loaded directly from
// global (16B/lane contiguous). LDS only for epilogue reassembly.

template <int RELU>
__global__ __launch_bounds__(256) void k_gemm(
    const unsigned short* __restrict__ hb, const unsigned short* __restrict__ aggb,
    const unsigned short* __restrict__ wt, const float* __restrict__ brel,
    unsigned short* __restrict__ hbout, int n) {
    __shared__ float sc[4][16 * 68];

    int tid = threadIdx.x;
    int w = tid >> 6, l = tid & 63;
    int lm = l & 15, q = l >> 4;
    int r0 = blockIdx.x * 64 + w * 16;

    // A fragments: row = r0+lm (clamped), 8 consecutive k at quad*8
    int arow = r0 + lm;
    if (arow >= n) arow = n - 1;
    const unsigned short* ah = hb + (size_t)arow * 64 + q * 8;
    const unsigned short* aa = aggb + (size_t)arow * 64 + q * 8;
    vbf8 afr[4];
    afr[0] = *(const vbf8*)(ah);
    afr[1] = *(const vbf8*)(ah + 32);
    afr[2] = *(const vbf8*)(aa);
    afr[3] = *(const vbf8*)(aa + 32);

    vf4 acc[4];
#pragma unroll
    for (int t = 0; t < 4; t++) acc[t] = (vf4){0.f, 0.f, 0.f, 0.f};

#pragma unroll
    for (int t = 0; t < 4; t++) {
        const unsigned short* wrow = wt + (size_t)(t * 16 + lm) * 128 + q * 8;
#pragma unroll
        for (int s = 0; s < 4; s++) {
            vbf8 bfr = *(const vbf8*)(wrow + s * 32);
            acc[t] = __builtin_amdgcn_mfma_f32_16x16x32_bf16(afr[s], bfr, acc[t], 0, 0, 0);
        }
    }

    // epilogue: bias + relu, stage fp32 in LDS (per-wave region, no barrier)
    float* sw_ = sc[w];
#pragma unroll
    for (int t = 0; t < 4; t++) {
        float b = brel[t * 16 + lm];
#pragma unroll
        for (int i = 0; i < 4; i++) {
            float v = acc[t][i] + b;
            if (RELU) v = fmaxf(v, 0.f);
            sw_[(q * 4 + i) * 68 + t * 16 + lm] = v;   // row=(q*4+i), col=t*16+lm
        }
    }
    // readback: lane -> row l>>2, 16-col segment (l&3); convert to bf16, store
    int rr = l >> 2, cs = l & 3;
    int node = r0 + rr;
    if (node < n) {
        const float* rp = sw_ + rr * 68 + cs * 16;
        float4 v0 = *(const float4*)(rp);
        float4 v1 = *(const float4*)(rp + 4);
        float4 v2 = *(const float4*)(rp + 8);
        float4 v3 = *(const float4*)(rp + 12);
        uint4 o0, o1;
        o0.x = (unsigned)f2b(v0.x) | ((unsigned)f2b(v0.y) << 16);
        o0.y = (unsigned)f2b(v0.z) | ((unsigned)f2b(v0.w) << 16);
        o0.z = (unsigned)f2b(v1.x) | ((unsigned)f2b(v1.y) << 16);
        o0.w = (unsigned)f2b(v1.z) | ((unsigned)f2b(v1.w) << 16);
        o1.x = (unsigned)f2b(v2.x) | ((unsigned)f2b(v2.y) << 16);
        o1.y = (unsigned)f2b(v2.z) | ((unsigned)f2b(v2.w) << 16);
        o1.z = (unsigned)f2b(v3.x) | ((unsigned)f2b(v3.y) << 16);
        o1.w = (unsigned)f2b(v3.z) | ((unsigned)f2b(v3.w) << 16);
        uint4* op = (uint4*)(hbout + (size_t)node * 64 + cs * 16);
        op[0] = o0;
        op[1] = o1;
    }
}

// ---------------- pooling ----------------

__global__ void k_bounds(const int* __restrict__ batch, int* __restrict__ gstart,
                         int* __restrict__ gend, int n) {
    int i = blockIdx.x * blockDim.x + threadIdx.x;
    if (i < n) {
        int b = batch[i];
        if (i == 0 || batch[i - 1] != b) gstart[b] = i;
        if (i == n - 1 || batch[i + 1] != b) gend[b] = i + 1;
    }
}

__global__ void k_pool(const unsigned short* __restrict__ hb,
                       const int* __restrict__ gstart,
                       const int* __restrict__ gend, const float* __restrict__ T,
                       float* __restrict__ pool) {
    int g = blockIdx.x;
    int l = threadIdx.x;  // 64 threads
    int s0 = gstart[g], s1 = gend[g];
    float s0a = 0.f, s1a = 0.f, s2a = 0.f, s3a = 0.f;
    float m0 = -INFINITY, m1 = -INFINITY, m2 = -INFINITY, m3 = -INFINITY;
    int n = s0;
    for (; n + 4 <= s1; n += 4) {
        float v0 = b2f(hb[(size_t)n * 64 + l]);
        float v1 = b2f(hb[(size_t)(n + 1) * 64 + l]);
        float v2 = b2f(hb[(size_t)(n + 2) * 64 + l]);
        float v3 = b2f(hb[(size_t)(n + 3) * 64 + l]);
        s0a += v0; s1a += v1; s2a += v2; s3a += v3;
        m0 = fmaxf(m0, v0); m1 = fmaxf(m1, v1);
        m2 = fmaxf(m2, v2); m3 = fmaxf(m3, v3);
    }
    for (; n < s1; n++) {
        float v = b2f(hb[(size_t)n * 64 + l]);
        s0a += v;
        m0 = fmaxf(m0, v);
    }
    float s = (s0a + s1a) + (s2a + s3a);
    float mx = fmaxf(fmaxf(m0, m1), fmaxf(m2, m3));
    int cnt = s1 - s0;
    float mean = s / fmaxf((float)cnt, 1.f);
    if (cnt == 0) mx = 0.f;
    float* row = pool + (size_t)g * 193;
    row[l] = mx;
    row[64 + l] = mean;
    row[128 + l] = s;
    if (l == 0) row[192] = T[g];
}

// ---------------- MLP head ----------------

__global__ __launch_bounds__(256) void k_mlp(
    const float* __restrict__ pool, const float* __restrict__ w1,
    const float* __restrict__ b1, const float* __restrict__ w2,
    const float* __restrict__ b2, const float* __restrict__ w3,
    const float* __restrict__ b3, float* __restrict__ out) {
    __shared__ float sin_[193];
    __shared__ float so1[256];
    __shared__ float red[256];
    int g = blockIdx.x, t = threadIdx.x;
    if (t < 193) sin_[t] = pool[(size_t)g * 193 + t];
    __syncthreads();
    float a = b1[t];
    for (int k = 0; k < 193; k++) a += sin_[k] * w1[k * 256 + t];
    a = fmaxf(a, 0.f);
    so1[t] = a;
    __syncthreads();
    float a2 = b2[t];
    for (int k = 0; k < 256; k++) a2 += so1[k] * w2[k * 256 + t];
    a2 = fmaxf(a2, 0.f);
    red[t] = a2 * w3[t];
    __syncthreads();
    for (int s = 128; s > 0; s >>= 1) {
        if (t < s) red[t] += red[t + s];
        __syncthreads();
    }
    if (t == 0) out[g] = red[0] + b3[0];
}

extern "C" void kernel_launch(void* const* d_in, const int* in_sizes, int n_in,
                              void* d_out, int out_size, void* d_ws, size_t ws_size,
                              hipStream_t stream) {
    const int N = N_NODES, E = N_EDGES, G = N_GRAPHS;

    const float* x = (const float*)d_in[0];
    const int* ei = (const int*)d_in[1];
    const int* batch = (const int*)d_in[2];
    const float* T = (const float*)d_in[3];
    const float* wrel[4] = {(const float*)d_in[4], (const float*)d_in[7],
                            (const float*)d_in[10], (const float*)d_in[13]};
    const float* brel[4] = {(const float*)d_in[5], (const float*)d_in[8],
                            (const float*)d_in[11], (const float*)d_in[14]};
    const float* wroot[4] = {(const float*)d_in[6], (const float*)d_in[9],
                             (const float*)d_in[12], (const float*)d_in[15]};
    const float* w1 = (const float*)d_in[16];
    const float* b1 = (const float*)d_in[17];
    const float* w2 = (const float*)d_in[18];
    const float* b2 = (const float*)d_in[19];
    const float* w3 = (const float*)d_in[20];
    const float* b3 = (const float*)d_in[21];
    float* out = (float*)d_out;

    const int* esrc = ei;
    const int* edst = ei + E;

    // workspace layout
    char* ws = (char*)d_ws;
    size_t off = 0;
    auto alloc = [&](size_t bytes) {
        size_t r = off;
        off = (off + bytes + 255) & ~(size_t)255;
        return r;
    };
    int* cnt = (int*)(ws + alloc((size_t)N * 4));
    int* rowptr = (int*)(ws + alloc((size_t)(N + 1) * 4));
    int* bsum = (int*)(ws + alloc(512));
    int* bcnt = (int*)(ws + alloc((size_t)NB * 4));
    int* boff = (int*)(ws + alloc((size_t)(NB + 1) * 4));
    int* bcur = (int*)(ws + alloc((size_t)NB * 4));
    int* ssrc = (int*)(ws + alloc((size_t)E * 4));
    int2* ebuf = (int2*)(ws + alloc((size_t)E * 8));
    unsigned short* hbA = (unsigned short*)(ws + alloc((size_t)N * 64 * 2));
    unsigned short* hbB = (unsigned short*)(ws + alloc((size_t)N * 64 * 2));
    unsigned short* aggb = (unsigned short*)(ws + alloc((size_t)N * 64 * 2));
    unsigned short* wt = (unsigned short*)(ws + alloc((size_t)4 * 64 * 128 * 2));
    int* gstart = (int*)(ws + alloc((size_t)G * 4));
    int* gend = (int*)(ws + alloc((size_t)G * 4));
    float* pool = (float*)(ws + alloc((size_t)G * 193 * 4));

    // 1. CSR build (bucketed)
    hipMemsetAsync(cnt, 0, (size_t)N * 4, stream);
    hipMemsetAsync(bcnt, 0, (size_t)NB * 4, stream);
    hipMemsetAsync(gstart, 0, (size_t)G * 4, stream);
    hipMemsetAsync(gend, 0, (size_t)G * 4, stream);
    int hist_blocks = (E + EDGES_PER_BLOCK - 1) / EDGES_PER_BLOCK;  // 391
    k_hist<<<hist_blocks, 256, 0, stream>>>(edst, cnt, bcnt, E);
    k_bscan<<<1, 1024, 0, stream>>>(bcnt, boff, bcur, E);
    int nb1 = (N + 1023) / 1024;
    k_scan1<<<nb1, 256, 0, stream>>>(cnt, rowptr, bsum, N);
    k_scan2<<<1, 128, 0, stream>>>(bsum, nb1);
    k_scan3<<<(N + 255) / 256, 256, 0, stream>>>(rowptr, bsum, N, E);
    k_bscatter<<<hist_blocks, 256, 0, stream>>>(esrc, edst, bcur, ebuf, E);
    k_fscatter<<<NB, 256, 0, stream>>>(ebuf, boff, rowptr, ssrc, N);

    // 2. convert input + weights to bf16
    int nq = N * 64 / 4;
    k_f2b<<<(nq + 255) / 256, 256, 0, stream>>>((const float4*)x, (ushort4*)hbA, nq);
    for (int i = 0; i < 4; i++)
        k_wprep<<<32, 256, 0, stream>>>(wroot[i], wrel[i], wt + i * 64 * 128);

    // 3. four conv layers (bf16 h ping-pong, MFMA gemm)
    int agg_blocks = (N * 64 + 255) / 256;   // one wave per node
    int gemm_blocks = (N + 63) / 64;         // 64-node tile per block

    k_agg<<<agg_blocks, 256, 0, stream>>>(hbA, aggb, rowptr, ssrc, N);
    k_gemm<1><<<gemm_blocks, 256, 0, stream>>>(hbA, aggb, wt + 0 * 8192, brel[0], hbB, N);

    k_agg<<<agg_blocks, 256, 0, stream>>>(hbB, aggb, rowptr, ssrc, N);
    k_gemm<1><<<gemm_blocks, 256, 0, stream>>>(hbB, aggb, wt + 1 * 8192, brel[1], hbA, N);

    k_agg<<<agg_blocks, 256, 0, stream>>>(hbA, aggb, rowptr, ssrc, N);
    k_gemm<1><<<gemm_blocks, 256, 0, stream>>>(hbA, aggb, wt + 2 * 8192, brel[2], hbB, N);

    k_agg<<<agg_blocks, 256, 0, stream>>>(hbB, aggb, rowptr, ssrc, N);
    k_gemm<0><<<gemm_blocks, 256, 0, stream>>>(hbB, aggb, wt + 3 * 8192, brel[3], hbA, N);

    // 4. pooling
    k_bounds<<<(N + 255) / 256, 256, 0, stream>>>(batch, gstart, gend, N);
    k_pool<<<G, 64, 0, stream>>>(hbA, gstart, gend, T, pool);

    // 5. MLP head
    k_mlp<<<G, 256, 0, stream>>>(pool, w1, b1, w2, b2, w3, b3, out);
}

// Round 6
// 563.474 us; speedup vs baseline: 3.9366x; 1.0908x over previous
//
#include <hip/hip_runtime.h>
#include <hip/hip_bf16.h>
#include <math.h>

#define N_NODES 100000
#define N_EDGES 1600000
#define N_FEAT 64
#define HID 64
#define HL 256
#define N_GRAPHS 512

#define BUCKET_BITS 7
#define BUCKET_SIZE 128
#define NB ((N_NODES + BUCKET_SIZE - 1) / BUCKET_SIZE)   // 782
#define EDGES_PER_BLOCK 4096

typedef short vbf8 __attribute__((ext_vector_type(8)));
typedef float vf4 __attribute__((ext_vector_type(4)));

// bf16 helpers (manual RNE; values are finite)
__device__ __forceinline__ unsigned short f2b(float f) {
    unsigned int u = __float_as_uint(f);
    return (unsigned short)((u + 0x7FFFu + ((u >> 16) & 1u)) >> 16);
}
__device__ __forceinline__ float b2f(unsigned short u) {
    return __uint_as_float(((unsigned int)u) << 16);
}

// ---------------- CSR build (bucketed, no per-node global atomics) --------

// bucket histogram only (LDS, flushed once per block)
__global__ __launch_bounds__(256) void k_bhist(const int* __restrict__ dst,
        int* __restrict__ bcnt, int e) {
    __shared__ int lh[NB];
    for (int t = threadIdx.x; t < NB; t += 256) lh[t] = 0;
    __syncthreads();
    int stride = gridDim.x * 256;
    for (int i = blockIdx.x * 256 + threadIdx.x; i < e; i += stride)
        atomicAdd(&lh[dst[i] >> BUCKET_BITS], 1);
    __syncthreads();
    for (int t = threadIdx.x; t < NB; t += 256)
        if (lh[t]) atomicAdd(&bcnt[t], lh[t]);
}

// exclusive scan of NB bucket counts (single 1024-thread block)
__global__ void k_bscan(const int* __restrict__ bcnt, int* __restrict__ boff,
                        int* __restrict__ bcur, int e) {
    __shared__ int sdata[1024];
    int t = threadIdx.x;
    int v = (t < NB) ? bcnt[t] : 0;
    sdata[t] = v;
    __syncthreads();
    for (int off = 1; off < 1024; off <<= 1) {
        int x = sdata[t];
        int y = (t >= off) ? sdata[t - off] : 0;
        __syncthreads();
        sdata[t] = x + y;
        __syncthreads();
    }
    if (t < NB) {
        int ex = sdata[t] - v;
        boff[t] = ex;
        bcur[t] = ex;
    }
    if (t == 0) boff[NB] = e;
}

// scatter (src,dst) records into bucket-ordered ebuf; per-block LDS claim
__global__ __launch_bounds__(256) void k_bscatter(const int* __restrict__ src,
        const int* __restrict__ dst, int* __restrict__ bcur,
        int2* __restrict__ ebuf, int e) {
    __shared__ int lh[NB];
    __shared__ int lbase[NB];
    for (int t = threadIdx.x; t < NB; t += 256) lh[t] = 0;
    __syncthreads();
    int i0 = blockIdx.x * EDGES_PER_BLOCK;
    int i1 = min(e, i0 + EDGES_PER_BLOCK);
    for (int i = i0 + threadIdx.x; i < i1; i += 256)
        atomicAdd(&lh[dst[i] >> BUCKET_BITS], 1);
    __syncthreads();
    for (int t = threadIdx.x; t < NB; t += 256) {
        int c = lh[t];
        lbase[t] = c ? atomicAdd(&bcur[t], c) : 0;
        lh[t] = 0;  // reuse as local cursor
    }
    __syncthreads();
    for (int i = i0 + threadIdx.x; i < i1; i += 256) {
        int s = src[i], d = dst[i];
        int b = d >> BUCKET_BITS;
        int p = lbase[b] + atomicAdd(&lh[b], 1);
        ebuf[p] = make_int2(s, d);
    }
}

// per-bucket: node hist (LDS) -> block scan -> rowptr write -> scatter ssrc.
// Replaces the old global node histogram + 3-kernel scan + fscatter.
__global__ __launch_bounds__(256) void k_fscatter2(const int2* __restrict__ ebuf,
        const int* __restrict__ boff, int* __restrict__ rowptr,
        int* __restrict__ ssrc, int n, int e) {
    __shared__ int lcnt[BUCKET_SIZE];
    __shared__ int sc[BUCKET_SIZE];
    __shared__ int cur[BUCKET_SIZE];
    int b = blockIdx.x;
    int n0 = b * BUCKET_SIZE;
    int t = threadIdx.x;
    if (t < BUCKET_SIZE) lcnt[t] = 0;
    __syncthreads();
    int r0 = boff[b], r1 = boff[b + 1];
    for (int r = r0 + t; r < r1; r += 256) {
        int2 rec = ebuf[r];
        atomicAdd(&lcnt[rec.y - n0], 1);
    }
    __syncthreads();
    int v = 0;
    if (t < BUCKET_SIZE) {
        v = lcnt[t];
        sc[t] = v;
    }
    __syncthreads();
    for (int off = 1; off < BUCKET_SIZE; off <<= 1) {
        int x = 0;
        if (t < BUCKET_SIZE) {
            x = sc[t];
            if (t >= off) x += sc[t - off];
        }
        __syncthreads();
        if (t < BUCKET_SIZE) sc[t] = x;
        __syncthreads();
    }
    if (t < BUCKET_SIZE) {
        int start = r0 + sc[t] - v;   // exclusive
        if (n0 + t < n) rowptr[n0 + t] = start;
        cur[t] = start;
    }
    if (b == 0 && t == 0) rowptr[n] = e;
    __syncthreads();
    for (int r = r0 + t; r < r1; r += 256) {
        int2 rec = ebuf[r];
        int p = atomicAdd(&cur[rec.y - n0], 1);
        ssrc[p] = rec.x;
    }
}

// ---------------- fp32 -> bf16 convert (layer-0 input) ----------------

__global__ __launch_bounds__(256) void k_f2b(const float4* __restrict__ x,
        ushort4* __restrict__ xb, int nq) {
    int i = blockIdx.x * 256 + threadIdx.x;
    if (i < nq) {
        float4 v = x[i];
        ushort4 o;
        o.x = f2b(v.x); o.y = f2b(v.y); o.z = f2b(v.z); o.w = f2b(v.w);
        xb[i] = o;
    }
}

// ---------------- weight prep: Wt[n][k] bf16, k = [wroot 0..63 | wrel 64..127]

__global__ __launch_bounds__(256) void k_wprep(const float* __restrict__ wroot,
        const float* __restrict__ wrel, unsigned short* __restrict__ wt) {
    int i = blockIdx.x * 256 + threadIdx.x;   // 0..8191
    if (i >= 64 * 128) return;
    int nn = i >> 7, k = i & 127;
    float v = (k < 64) ? wroot[k * 64 + nn] : wrel[(k - 64) * 64 + nn];
    wt[i] = f2b(v);
}

// ---------------- aggregation: aggb[i] = sum_{j->i} h[j] (bf16 in/out) -----
// one wave per node; 16 independent gathers in flight (avg degree = 16)

__global__ __launch_bounds__(256) void k_agg(
    const unsigned short* __restrict__ hb, unsigned short* __restrict__ aggb,
    const int* __restrict__ rowptr, const int* __restrict__ ssrc, int n) {
    int lane = threadIdx.x & 63;
    int i = (blockIdx.x * 256 + threadIdx.x) >> 6;
    if (i >= n) return;
    int e0 = rowptr[i], e1 = rowptr[i + 1];
    float a[16];
#pragma unroll
    for (int u = 0; u < 16; u++) a[u] = 0.f;
    int e = e0;
    for (; e + 16 <= e1; e += 16) {
#pragma unroll
        for (int u = 0; u < 16; u++) {
            int j = ssrc[e + u];
            a[u] += b2f(hb[(size_t)j * 64 + lane]);
        }
    }
    for (; e + 4 <= e1; e += 4) {
#pragma unroll
        for (int u = 0; u < 4; u++) {
            int j = ssrc[e + u];
            a[u] += b2f(hb[(size_t)j * 64 + lane]);
        }
    }
    for (; e < e1; e++) a[0] += b2f(hb[(size_t)ssrc[e] * 64 + lane]);
#pragma unroll
    for (int u = 8; u < 16; u++) a[u - 8] += a[u];
#pragma unroll
    for (int u = 4; u < 8; u++) a[u - 4] += a[u];
    float s = (a[0] + a[1]) + (a[2] + a[3]);
    aggb[(size_t)i * 64 + lane] = f2b(s);
}

// ---------------- MFMA gemm: hbout = [relu]([hb|aggb] @ Wt^T + brel) -------

template <int RELU>
__global__ __launch_bounds__(256) void k_gemm(
    const unsigned short* __restrict__ hb, const unsigned short* __restrict__ aggb,
    const unsigned short* __restrict__ wt, const float* __restrict__ brel,
    unsigned short* __restrict__ hbout, int n) {
    __shared__ float sc[4][16 * 68];

    int tid = threadIdx.x;
    int w = tid >> 6, l = tid & 63;
    int lm = l & 15, q = l >> 4;
    int r0 = blockIdx.x * 64 + w * 16;

    int arow = r0 + lm;
    if (arow >= n) arow = n - 1;
    const unsigned short* ah = hb + (size_t)arow * 64 + q * 8;
    const unsigned short* aa = aggb + (size_t)arow * 64 + q * 8;
    vbf8 afr[4];
    afr[0] = *(const vbf8*)(ah);
    afr[1] = *(const vbf8*)(ah + 32);
    afr[2] = *(const vbf8*)(aa);
    afr[3] = *(const vbf8*)(aa + 32);

    vf4 acc[4];
#pragma unroll
    for (int t = 0; t < 4; t++) acc[t] = (vf4){0.f, 0.f, 0.f, 0.f};

#pragma unroll
    for (int t = 0; t < 4; t++) {
        const unsigned short* wrow = wt + (size_t)(t * 16 + lm) * 128 + q * 8;
#pragma unroll
        for (int s = 0; s < 4; s++) {
            vbf8 bfr = *(const vbf8*)(wrow + s * 32);
            acc[t] = __builtin_amdgcn_mfma_f32_16x16x32_bf16(afr[s], bfr, acc[t], 0, 0, 0);
        }
    }

    float* sw_ = sc[w];
#pragma unroll
    for (int t = 0; t < 4; t++) {
        float b = brel[t * 16 + lm];
#pragma unroll
        for (int i = 0; i < 4; i++) {
            float v = acc[t][i] + b;
            if (RELU) v = fmaxf(v, 0.f);
            sw_[(q * 4 + i) * 68 + t * 16 + lm] = v;
        }
    }
    int rr = l >> 2, cs = l & 3;
    int node = r0 + rr;
    if (node < n) {
        const float* rp = sw_ + rr * 68 + cs * 16;
        float4 v0 = *(const float4*)(rp);
        float4 v1 = *(const float4*)(rp + 4);
        float4 v2 = *(const float4*)(rp + 8);
        float4 v3 = *(const float4*)(rp + 12);
        uint4 o0, o1;
        o0.x = (unsigned)f2b(v0.x) | ((unsigned)f2b(v0.y) << 16);
        o0.y = (unsigned)f2b(v0.z) | ((unsigned)f2b(v0.w) << 16);
        o0.z = (unsigned)f2b(v1.x) | ((unsigned)f2b(v1.y) << 16);
        o0.w = (unsigned)f2b(v1.z) | ((unsigned)f2b(v1.w) << 16);
        o1.x = (unsigned)f2b(v2.x) | ((unsigned)f2b(v2.y) << 16);
        o1.y = (unsigned)f2b(v2.z) | ((unsigned)f2b(v2.w) << 16);
        o1.z = (unsigned)f2b(v3.x) | ((unsigned)f2b(v3.y) << 16);
        o1.w = (unsigned)f2b(v3.z) | ((unsigned)f2b(v3.w) << 16);
        uint4* op = (uint4*)(hbout + (size_t)node * 64 + cs * 16);
        op[0] = o0;
        op[1] = o1;
    }
}

// ---------------- pooling ----------------

__global__ void k_bounds(const int* __restrict__ batch, int* __restrict__ gstart,
                         int* __restrict__ gend, int n) {
    int i = blockIdx.x * blockDim.x + threadIdx.x;
    if (i < n) {
        int b = batch[i];
        if (i == 0 || batch[i - 1] != b) gstart[b] = i;
        if (i == n - 1 || batch[i + 1] != b) gend[b] = i + 1;
    }
}

__global__ void k_pool(const unsigned short* __restrict__ hb,
                       const int* __restrict__ gstart,
                       const int* __restrict__ gend, const float* __restrict__ T,
                       float* __restrict__ pool) {
    int g = blockIdx.x;
    int l = threadIdx.x;  // 64 threads
    int s0 = gstart[g], s1 = gend[g];
    float s0a = 0.f, s1a = 0.f, s2a = 0.f, s3a = 0.f;
    float m0 = -INFINITY, m1 = -INFINITY, m2 = -INFINITY, m3 = -INFINITY;
    int n = s0;
    for (; n + 4 <= s1; n += 4) {
        float v0 = b2f(hb[(size_t)n * 64 + l]);
        float v1 = b2f(hb[(size_t)(n + 1) * 64 + l]);
        float v2 = b2f(hb[(size_t)(n + 2) * 64 + l]);
        float v3 = b2f(hb[(size_t)(n + 3) * 64 + l]);
        s0a += v0; s1a += v1; s2a += v2; s3a += v3;
        m0 = fmaxf(m0, v0); m1 = fmaxf(m1, v1);
        m2 = fmaxf(m2, v2); m3 = fmaxf(m3, v3);
    }
    for (; n < s1; n++) {
        float v = b2f(hb[(size_t)n * 64 + l]);
        s0a += v;
        m0 = fmaxf(m0, v);
    }
    float s = (s0a + s1a) + (s2a + s3a);
    float mx = fmaxf(fmaxf(m0, m1), fmaxf(m2, m3));
    int cnt = s1 - s0;
    float mean = s / fmaxf((float)cnt, 1.f);
    if (cnt == 0) mx = 0.f;
    float* row = pool + (size_t)g * 193;
    row[l] = mx;
    row[64 + l] = mean;
    row[128 + l] = s;
    if (l == 0) row[192] = T[g];
}

// ---------------- MLP head ----------------

__global__ __launch_bounds__(256) void k_mlp(
    const float* __restrict__ pool, const float* __restrict__ w1,
    const float* __restrict__ b1, const float* __restrict__ w2,
    const float* __restrict__ b2, const float* __restrict__ w3,
    const float* __restrict__ b3, float* __restrict__ out) {
    __shared__ float sin_[193];
    __shared__ float so1[256];
    __shared__ float red[256];
    int g = blockIdx.x, t = threadIdx.x;
    if (t < 193) sin_[t] = pool[(size_t)g * 193 + t];
    __syncthreads();
    float a = b1[t];
    for (int k = 0; k < 193; k++) a += sin_[k] * w1[k * 256 + t];
    a = fmaxf(a, 0.f);
    so1[t] = a;
    __syncthreads();
    float a2 = b2[t];
    for (int k = 0; k < 256; k++) a2 += so1[k] * w2[k * 256 + t];
    a2 = fmaxf(a2, 0.f);
    red[t] = a2 * w3[t];
    __syncthreads();
    for (int s = 128; s > 0; s >>= 1) {
        if (t < s) red[t] += red[t + s];
        __syncthreads();
    }
    if (t == 0) out[g] = red[0] + b3[0];
}

extern "C" void kernel_launch(void* const* d_in, const int* in_sizes, int n_in,
                              void* d_out, int out_size, void* d_ws, size_t ws_size,
                              hipStream_t stream) {
    const int N = N_NODES, E = N_EDGES, G = N_GRAPHS;

    const float* x = (const float*)d_in[0];
    const int* ei = (const int*)d_in[1];
    const int* batch = (const int*)d_in[2];
    const float* T = (const float*)d_in[3];
    const float* wrel[4] = {(const float*)d_in[4], (const float*)d_in[7],
                            (const float*)d_in[10], (const float*)d_in[13]};
    const float* brel[4] = {(const float*)d_in[5], (const float*)d_in[8],
                            (const float*)d_in[11], (const float*)d_in[14]};
    const float* wroot[4] = {(const float*)d_in[6], (const float*)d_in[9],
                             (const float*)d_in[12], (const float*)d_in[15]};
    const float* w1 = (const float*)d_in[16];
    const float* b1 = (const float*)d_in[17];
    const float* w2 = (const float*)d_in[18];
    const float* b2 = (const float*)d_in[19];
    const float* w3 = (const float*)d_in[20];
    const float* b3 = (const float*)d_in[21];
    float* out = (float*)d_out;

    const int* esrc = ei;
    const int* edst = ei + E;

    // workspace layout
    char* ws = (char*)d_ws;
    size_t off = 0;
    auto alloc = [&](size_t bytes) {
        size_t r = off;
        off = (off + bytes + 255) & ~(size_t)255;
        return r;
    };
    int* rowptr = (int*)(ws + alloc((size_t)(N + 1) * 4));
    int* bcnt = (int*)(ws + alloc((size_t)NB * 4));
    int* boff = (int*)(ws + alloc((size_t)(NB + 1) * 4));
    int* bcur = (int*)(ws + alloc((size_t)NB * 4));
    int* ssrc = (int*)(ws + alloc((size_t)E * 4));
    int2* ebuf = (int2*)(ws + alloc((size_t)E * 8));
    unsigned short* hbA = (unsigned short*)(ws + alloc((size_t)N * 64 * 2));
    unsigned short* hbB = (unsigned short*)(ws + alloc((size_t)N * 64 * 2));
    unsigned short* aggb = (unsigned short*)(ws + alloc((size_t)N * 64 * 2));
    unsigned short* wt = (unsigned short*)(ws + alloc((size_t)4 * 64 * 128 * 2));
    int* gstart = (int*)(ws + alloc((size_t)G * 4));
    int* gend = (int*)(ws + alloc((size_t)G * 4));
    float* pool = (float*)(ws + alloc((size_t)G * 193 * 4));

    // 1. CSR build (bucketed; no per-node global atomics, no scan kernels)
    hipMemsetAsync(bcnt, 0, (size_t)NB * 4, stream);
    hipMemsetAsync(gstart, 0, (size_t)G * 4, stream);
    hipMemsetAsync(gend, 0, (size_t)G * 4, stream);
    int hist_blocks = (E + EDGES_PER_BLOCK - 1) / EDGES_PER_BLOCK;  // 391
    k_bhist<<<hist_blocks, 256, 0, stream>>>(edst, bcnt, E);
    k_bscan<<<1, 1024, 0, stream>>>(bcnt, boff, bcur, E);
    k_bscatter<<<hist_blocks, 256, 0, stream>>>(esrc, edst, bcur, ebuf, E);
    k_fscatter2<<<NB, 256, 0, stream>>>(ebuf, boff, rowptr, ssrc, N, E);

    // 2. convert input + weights to bf16
    int nq = N * 64 / 4;
    k_f2b<<<(nq + 255) / 256, 256, 0, stream>>>((const float4*)x, (ushort4*)hbA, nq);
    for (int i = 0; i < 4; i++)
        k_wprep<<<32, 256, 0, stream>>>(wroot[i], wrel[i], wt + i * 64 * 128);

    // 3. four conv layers (bf16 h ping-pong, MFMA gemm)
    int agg_blocks = (N * 64 + 255) / 256;   // one wave per node
    int gemm_blocks = (N + 63) / 64;         // 64-node tile per block

    k_agg<<<agg_blocks, 256, 0, stream>>>(hbA, aggb, rowptr, ssrc, N);
    k_gemm<1><<<gemm_blocks, 256, 0, stream>>>(hbA, aggb, wt + 0 * 8192, brel[0], hbB, N);

    k_agg<<<agg_blocks, 256, 0, stream>>>(hbB, aggb, rowptr, ssrc, N);
    k_gemm<1><<<gemm_blocks, 256, 0, stream>>>(hbB, aggb, wt + 1 * 8192, brel[1], hbA, N);

    k_agg<<<agg_blocks, 256, 0, stream>>>(hbA, aggb, rowptr, ssrc, N);
    k_gemm<1><<<gemm_blocks, 256, 0, stream>>>(hbA, aggb, wt + 2 * 8192, brel[2], hbB, N);

    k_agg<<<agg_blocks, 256, 0, stream>>>(hbB, aggb, rowptr, ssrc, N);
    k_gemm<0><<<gemm_blocks, 256, 0, stream>>>(hbB, aggb, wt + 3 * 8192, brel[3], hbA, N);

    // 4. pooling
    k_bounds<<<(N + 255) / 256, 256, 0, stream>>>(batch, gstart, gend, N);
    k_pool<<<G, 64, 0, stream>>>(hbA, gstart, gend, T, pool);

    // 5. MLP head
    k_mlp<<<G, 256, 0, stream>>>(pool, w1, b1, w2, b2, w3, b3, out);
}

// Round 7
// 492.088 us; speedup vs baseline: 4.5077x; 1.1451x over previous
//
#include <hip/hip_runtime.h>
#include <hip/hip_bf16.h>
#include <math.h>

#define N_NODES 100000
#define N_EDGES 1600000
#define N_FEAT 64
#define HID 64
#define HL 256
#define N_GRAPHS 512

#define BUCKET_BITS 7
#define BUCKET_SIZE 128
#define NB ((N_NODES + BUCKET_SIZE - 1) / BUCKET_SIZE)   // 782
#define EDGES_PER_BLOCK 4096

typedef short vbf8 __attribute__((ext_vector_type(8)));
typedef float vf4 __attribute__((ext_vector_type(4)));

// bf16 helpers (manual RNE; values are finite)
__device__ __forceinline__ unsigned short f2b(float f) {
    unsigned int u = __float_as_uint(f);
    return (unsigned short)((u + 0x7FFFu + ((u >> 16) & 1u)) >> 16);
}
__device__ __forceinline__ float b2f(unsigned short u) {
    return __uint_as_float(((unsigned int)u) << 16);
}

// ---------------- CSR build (bucketed, no per-node global atomics) --------

__global__ __launch_bounds__(256) void k_bhist(const int* __restrict__ dst,
        int* __restrict__ bcnt, int e) {
    __shared__ int lh[NB];
    for (int t = threadIdx.x; t < NB; t += 256) lh[t] = 0;
    __syncthreads();
    int stride = gridDim.x * 256;
    for (int i = blockIdx.x * 256 + threadIdx.x; i < e; i += stride)
        atomicAdd(&lh[dst[i] >> BUCKET_BITS], 1);
    __syncthreads();
    for (int t = threadIdx.x; t < NB; t += 256)
        if (lh[t]) atomicAdd(&bcnt[t], lh[t]);
}

__global__ void k_bscan(const int* __restrict__ bcnt, int* __restrict__ boff,
                        int* __restrict__ bcur, int e) {
    __shared__ int sdata[1024];
    int t = threadIdx.x;
    int v = (t < NB) ? bcnt[t] : 0;
    sdata[t] = v;
    __syncthreads();
    for (int off = 1; off < 1024; off <<= 1) {
        int x = sdata[t];
        int y = (t >= off) ? sdata[t - off] : 0;
        __syncthreads();
        sdata[t] = x + y;
        __syncthreads();
    }
    if (t < NB) {
        int ex = sdata[t] - v;
        boff[t] = ex;
        bcur[t] = ex;
    }
    if (t == 0) boff[NB] = e;
}

__global__ __launch_bounds__(256) void k_bscatter(const int* __restrict__ src,
        const int* __restrict__ dst, int* __restrict__ bcur,
        int2* __restrict__ ebuf, int e) {
    __shared__ int lh[NB];
    __shared__ int lbase[NB];
    for (int t = threadIdx.x; t < NB; t += 256) lh[t] = 0;
    __syncthreads();
    int i0 = blockIdx.x * EDGES_PER_BLOCK;
    int i1 = min(e, i0 + EDGES_PER_BLOCK);
    for (int i = i0 + threadIdx.x; i < i1; i += 256)
        atomicAdd(&lh[dst[i] >> BUCKET_BITS], 1);
    __syncthreads();
    for (int t = threadIdx.x; t < NB; t += 256) {
        int c = lh[t];
        lbase[t] = c ? atomicAdd(&bcur[t], c) : 0;
        lh[t] = 0;  // reuse as local cursor
    }
    __syncthreads();
    for (int i = i0 + threadIdx.x; i < i1; i += 256) {
        int s = src[i], d = dst[i];
        int b = d >> BUCKET_BITS;
        int p = lbase[b] + atomicAdd(&lh[b], 1);
        ebuf[p] = make_int2(s, d);
    }
}

// per-bucket: node hist (LDS) -> block scan -> rowptr write -> scatter soff
// (soff stores src byte offsets, src<<7, for the 128B bf16 rows)
__global__ __launch_bounds__(256) void k_fscatter2(const int2* __restrict__ ebuf,
        const int* __restrict__ boff, int* __restrict__ rowptr,
        unsigned int* __restrict__ soff, int n, int e) {
    __shared__ int lcnt[BUCKET_SIZE];
    __shared__ int sc[BUCKET_SIZE];
    __shared__ int cur[BUCKET_SIZE];
    int b = blockIdx.x;
    int n0 = b * BUCKET_SIZE;
    int t = threadIdx.x;
    if (t < BUCKET_SIZE) lcnt[t] = 0;
    __syncthreads();
    int r0 = boff[b], r1 = boff[b + 1];
    for (int r = r0 + t; r < r1; r += 256) {
        int2 rec = ebuf[r];
        atomicAdd(&lcnt[rec.y - n0], 1);
    }
    __syncthreads();
    int v = 0;
    if (t < BUCKET_SIZE) {
        v = lcnt[t];
        sc[t] = v;
    }
    __syncthreads();
    for (int off = 1; off < BUCKET_SIZE; off <<= 1) {
        int x = 0;
        if (t < BUCKET_SIZE) {
            x = sc[t];
            if (t >= off) x += sc[t - off];
        }
        __syncthreads();
        if (t < BUCKET_SIZE) sc[t] = x;
        __syncthreads();
    }
    if (t < BUCKET_SIZE) {
        int start = r0 + sc[t] - v;   // exclusive
        if (n0 + t < n) rowptr[n0 + t] = start;
        cur[t] = start;
    }
    if (b == 0 && t == 0) rowptr[n] = e;
    __syncthreads();
    for (int r = r0 + t; r < r1; r += 256) {
        int2 rec = ebuf[r];
        int p = atomicAdd(&cur[rec.y - n0], 1);
        soff[p] = (unsigned int)rec.x << 7;
    }
}

// ---------------- fp32 -> bf16 convert (layer-0 input) ----------------

__global__ __launch_bounds__(256) void k_f2b(const float4* __restrict__ x,
        ushort4* __restrict__ xb, int nq) {
    int i = blockIdx.x * 256 + threadIdx.x;
    if (i < nq) {
        float4 v = x[i];
        ushort4 o;
        o.x = f2b(v.x); o.y = f2b(v.y); o.z = f2b(v.z); o.w = f2b(v.w);
        xb[i] = o;
    }
}

// ---------------- weight prep: Wt[n][k] bf16, k = [wroot 0..63 | wrel 64..127]

__global__ __launch_bounds__(256) void k_wprep(const float* __restrict__ wroot,
        const float* __restrict__ wrel, unsigned short* __restrict__ wt) {
    int i = blockIdx.x * 256 + threadIdx.x;   // 0..8191
    if (i >= 64 * 128) return;
    int nn = i >> 7, k = i & 127;
    float v = (k < 64) ? wroot[k * 64 + nn] : wrel[(k - 64) * 64 + nn];
    wt[i] = f2b(v);
}

// ---------------- aggregation: aggb[i] = sum_{j->i} h[j] (bf16 in/out) -----
// one wave per node; 4 edges per VMEM instruction: lane = q*16+sl,
// q = edge slot (0..3), sl = feature quad (features 4sl..4sl+3, uint2 load).
// soff holds byte offsets (src<<7). Tail edges zeroed via cndmask (exact +0).

__global__ __launch_bounds__(256) void k_agg(
    const unsigned short* __restrict__ hb, unsigned short* __restrict__ aggb,
    const int* __restrict__ rowptr, const unsigned int* __restrict__ soff, int n) {
    int lane = threadIdx.x & 63;
    int i = (blockIdx.x * 256 + threadIdx.x) >> 6;
    if (i >= n) return;
    int q = lane >> 4;
    int sl = lane & 15;
    int e0 = rowptr[i], e1 = rowptr[i + 1];
    int deg = e1 - e0;
    int iters = (deg + 3) >> 2;
    const char* base = (const char*)hb + sl * 8;

    float A[4][4];
#pragma unroll
    for (int u = 0; u < 4; u++)
#pragma unroll
        for (int f = 0; f < 4; f++) A[u][f] = 0.f;

    int eq = e0 + q;
    int it = 0;
    for (; it + 4 <= iters; it += 4) {
#pragma unroll
        for (int u = 0; u < 4; u++) {
            int ee = eq + (it + u) * 4;
            unsigned int off = soff[ee];          // padded: safe past e1
            uint2 dv = *(const uint2*)(base + off);
            if (ee >= e1) { dv.x = 0u; dv.y = 0u; }
            A[u][0] += __uint_as_float(dv.x << 16);
            A[u][1] += __uint_as_float(dv.x & 0xFFFF0000u);
            A[u][2] += __uint_as_float(dv.y << 16);
            A[u][3] += __uint_as_float(dv.y & 0xFFFF0000u);
        }
    }
    for (; it < iters; it++) {
        int ee = eq + it * 4;
        unsigned int off = soff[ee];
        uint2 dv = *(const uint2*)(base + off);
        if (ee >= e1) { dv.x = 0u; dv.y = 0u; }
        A[0][0] += __uint_as_float(dv.x << 16);
        A[0][1] += __uint_as_float(dv.x & 0xFFFF0000u);
        A[0][2] += __uint_as_float(dv.y << 16);
        A[0][3] += __uint_as_float(dv.y & 0xFFFF0000u);
    }

    float s0 = (A[0][0] + A[1][0]) + (A[2][0] + A[3][0]);
    float s1 = (A[0][1] + A[1][1]) + (A[2][1] + A[3][1]);
    float s2 = (A[0][2] + A[1][2]) + (A[2][2] + A[3][2]);
    float s3 = (A[0][3] + A[1][3]) + (A[2][3] + A[3][3]);
    // fold edge-slot dimension (lane bits 4,5)
    s0 += __shfl_xor(s0, 16); s0 += __shfl_xor(s0, 32);
    s1 += __shfl_xor(s1, 16); s1 += __shfl_xor(s1, 32);
    s2 += __shfl_xor(s2, 16); s2 += __shfl_xor(s2, 32);
    s3 += __shfl_xor(s3, 16); s3 += __shfl_xor(s3, 32);

    if (q == 0) {
        uint2 o;
        o.x = (unsigned)f2b(s0) | ((unsigned)f2b(s1) << 16);
        o.y = (unsigned)f2b(s2) | ((unsigned)f2b(s3) << 16);
        *(uint2*)((char*)aggb + (size_t)i * 128 + sl * 8) = o;
    }
}

// ---------------- MFMA gemm: hbout = [relu]([hb|aggb] @ Wt^T + brel) -------

template <int RELU>
__global__ __launch_bounds__(256) void k_gemm(
    const unsigned short* __restrict__ hb, const unsigned short* __restrict__ aggb,
    const unsigned short* __restrict__ wt, const float* __restrict__ brel,
    unsigned short* __restrict__ hbout, int n) {
    __shared__ float sc[4][16 * 68];

    int tid = threadIdx.x;
    int w = tid >> 6, l = tid & 63;
    int lm = l & 15, q = l >> 4;
    int r0 = blockIdx.x * 64 + w * 16;

    int arow = r0 + lm;
    if (arow >= n) arow = n - 1;
    const unsigned short* ah = hb + (size_t)arow * 64 + q * 8;
    const unsigned short* aa = aggb + (size_t)arow * 64 + q * 8;
    vbf8 afr[4];
    afr[0] = *(const vbf8*)(ah);
    afr[1] = *(const vbf8*)(ah + 32);
    afr[2] = *(const vbf8*)(aa);
    afr[3] = *(const vbf8*)(aa + 32);

    vf4 acc[4];
#pragma unroll
    for (int t = 0; t < 4; t++) acc[t] = (vf4){0.f, 0.f, 0.f, 0.f};

#pragma unroll
    for (int t = 0; t < 4; t++) {
        const unsigned short* wrow = wt + (size_t)(t * 16 + lm) * 128 + q * 8;
#pragma unroll
        for (int s = 0; s < 4; s++) {
            vbf8 bfr = *(const vbf8*)(wrow + s * 32);
            acc[t] = __builtin_amdgcn_mfma_f32_16x16x32_bf16(afr[s], bfr, acc[t], 0, 0, 0);
        }
    }

    float* sw_ = sc[w];
#pragma unroll
    for (int t = 0; t < 4; t++) {
        float b = brel[t * 16 + lm];
#pragma unroll
        for (int i = 0; i < 4; i++) {
            float v = acc[t][i] + b;
            if (RELU) v = fmaxf(v, 0.f);
            sw_[(q * 4 + i) * 68 + t * 16 + lm] = v;
        }
    }
    int rr = l >> 2, cs = l & 3;
    int node = r0 + rr;
    if (node < n) {
        const float* rp = sw_ + rr * 68 + cs * 16;
        float4 v0 = *(const float4*)(rp);
        float4 v1 = *(const float4*)(rp + 4);
        float4 v2 = *(const float4*)(rp + 8);
        float4 v3 = *(const float4*)(rp + 12);
        uint4 o0, o1;
        o0.x = (unsigned)f2b(v0.x) | ((unsigned)f2b(v0.y) << 16);
        o0.y = (unsigned)f2b(v0.z) | ((unsigned)f2b(v0.w) << 16);
        o0.z = (unsigned)f2b(v1.x) | ((unsigned)f2b(v1.y) << 16);
        o0.w = (unsigned)f2b(v1.z) | ((unsigned)f2b(v1.w) << 16);
        o1.x = (unsigned)f2b(v2.x) | ((unsigned)f2b(v2.y) << 16);
        o1.y = (unsigned)f2b(v2.z) | ((unsigned)f2b(v2.w) << 16);
        o1.z = (unsigned)f2b(v3.x) | ((unsigned)f2b(v3.y) << 16);
        o1.w = (unsigned)f2b(v3.z) | ((unsigned)f2b(v3.w) << 16);
        uint4* op = (uint4*)(hbout + (size_t)node * 64 + cs * 16);
        op[0] = o0;
        op[1] = o1;
    }
}

// ---------------- pooling ----------------

__global__ void k_bounds(const int* __restrict__ batch, int* __restrict__ gstart,
                         int* __restrict__ gend, int n) {
    int i = blockIdx.x * blockDim.x + threadIdx.x;
    if (i < n) {
        int b = batch[i];
        if (i == 0 || batch[i - 1] != b) gstart[b] = i;
        if (i == n - 1 || batch[i + 1] != b) gend[b] = i + 1;
    }
}

__global__ void k_pool(const unsigned short* __restrict__ hb,
                       const int* __restrict__ gstart,
                       const int* __restrict__ gend, const float* __restrict__ T,
                       float* __restrict__ pool) {
    int g = blockIdx.x;
    int l = threadIdx.x;  // 64 threads
    int s0 = gstart[g], s1 = gend[g];
    float s0a = 0.f, s1a = 0.f, s2a = 0.f, s3a = 0.f;
    float m0 = -INFINITY, m1 = -INFINITY, m2 = -INFINITY, m3 = -INFINITY;
    int n = s0;
    for (; n + 4 <= s1; n += 4) {
        float v0 = b2f(hb[(size_t)n * 64 + l]);
        float v1 = b2f(hb[(size_t)(n + 1) * 64 + l]);
        float v2 = b2f(hb[(size_t)(n + 2) * 64 + l]);
        float v3 = b2f(hb[(size_t)(n + 3) * 64 + l]);
        s0a += v0; s1a += v1; s2a += v2; s3a += v3;
        m0 = fmaxf(m0, v0); m1 = fmaxf(m1, v1);
        m2 = fmaxf(m2, v2); m3 = fmaxf(m3, v3);
    }
    for (; n < s1; n++) {
        float v = b2f(hb[(size_t)n * 64 + l]);
        s0a += v;
        m0 = fmaxf(m0, v);
    }
    float s = (s0a + s1a) + (s2a + s3a);
    float mx = fmaxf(fmaxf(m0, m1), fmaxf(m2, m3));
    int cnt = s1 - s0;
    float mean = s / fmaxf((float)cnt, 1.f);
    if (cnt == 0) mx = 0.f;
    float* row = pool + (size_t)g * 193;
    row[l] = mx;
    row[64 + l] = mean;
    row[128 + l] = s;
    if (l == 0) row[192] = T[g];
}

// ---------------- MLP head ----------------

__global__ __launch_bounds__(256) void k_mlp(
    const float* __restrict__ pool, const float* __restrict__ w1,
    const float* __restrict__ b1, const float* __restrict__ w2,
    const float* __restrict__ b2, const float* __restrict__ w3,
    const float* __restrict__ b3, float* __restrict__ out) {
    __shared__ float sin_[193];
    __shared__ float so1[256];
    __shared__ float red[256];
    int g = blockIdx.x, t = threadIdx.x;
    if (t < 193) sin_[t] = pool[(size_t)g * 193 + t];
    __syncthreads();
    float a = b1[t];
    for (int k = 0; k < 193; k++) a += sin_[k] * w1[k * 256 + t];
    a = fmaxf(a, 0.f);
    so1[t] = a;
    __syncthreads();
    float a2 = b2[t];
    for (int k = 0; k < 256; k++) a2 += so1[k] * w2[k * 256 + t];
    a2 = fmaxf(a2, 0.f);
    red[t] = a2 * w3[t];
    __syncthreads();
    for (int s = 128; s > 0; s >>= 1) {
        if (t < s) red[t] += red[t + s];
        __syncthreads();
    }
    if (t == 0) out[g] = red[0] + b3[0];
}

extern "C" void kernel_launch(void* const* d_in, const int* in_sizes, int n_in,
                              void* d_out, int out_size, void* d_ws, size_t ws_size,
                              hipStream_t stream) {
    const int N = N_NODES, E = N_EDGES, G = N_GRAPHS;

    const float* x = (const float*)d_in[0];
    const int* ei = (const int*)d_in[1];
    const int* batch = (const int*)d_in[2];
    const float* T = (const float*)d_in[3];
    const float* wrel[4] = {(const float*)d_in[4], (const float*)d_in[7],
                            (const float*)d_in[10], (const float*)d_in[13]};
    const float* brel[4] = {(const float*)d_in[5], (const float*)d_in[8],
                            (const float*)d_in[11], (const float*)d_in[14]};
    const float* wroot[4] = {(const float*)d_in[6], (const float*)d_in[9],
                             (const float*)d_in[12], (const float*)d_in[15]};
    const float* w1 = (const float*)d_in[16];
    const float* b1 = (const float*)d_in[17];
    const float* w2 = (const float*)d_in[18];
    const float* b2 = (const float*)d_in[19];
    const float* w3 = (const float*)d_in[20];
    const float* b3 = (const float*)d_in[21];
    float* out = (float*)d_out;

    const int* esrc = ei;
    const int* edst = ei + E;

    // workspace layout
    char* ws = (char*)d_ws;
    size_t off = 0;
    auto alloc = [&](size_t bytes) {
        size_t r = off;
        off = (off + bytes + 255) & ~(size_t)255;
        return r;
    };
    int* rowptr = (int*)(ws + alloc((size_t)(N + 1) * 4));
    int* bcnt = (int*)(ws + alloc((size_t)NB * 4));
    int* boff = (int*)(ws + alloc((size_t)(NB + 1) * 4));
    int* bcur = (int*)(ws + alloc((size_t)NB * 4));
    unsigned int* soff = (unsigned int*)(ws + alloc((size_t)(E + 8) * 4));
    int2* ebuf = (int2*)(ws + alloc((size_t)E * 8));
    unsigned short* hbA = (unsigned short*)(ws + alloc((size_t)N * 64 * 2));
    unsigned short* hbB = (unsigned short*)(ws + alloc((size_t)N * 64 * 2));
    unsigned short* aggb = (unsigned short*)(ws + alloc((size_t)N * 64 * 2));
    unsigned short* wt = (unsigned short*)(ws + alloc((size_t)4 * 64 * 128 * 2));
    int* gstart = (int*)(ws + alloc((size_t)G * 4));
    int* gend = (int*)(ws + alloc((size_t)G * 4));
    float* pool = (float*)(ws + alloc((size_t)G * 193 * 4));

    // 1. CSR build (bucketed)
    hipMemsetAsync(bcnt, 0, (size_t)NB * 4, stream);
    hipMemsetAsync(gstart, 0, (size_t)G * 4, stream);
    hipMemsetAsync(gend, 0, (size_t)G * 4, stream);
    hipMemsetAsync(soff + E, 0, 32, stream);   // pad: reads past e1 hit row 0
    int hist_blocks = (E + EDGES_PER_BLOCK - 1) / EDGES_PER_BLOCK;  // 391
    k_bhist<<<hist_blocks, 256, 0, stream>>>(edst, bcnt, E);
    k_bscan<<<1, 1024, 0, stream>>>(bcnt, boff, bcur, E);
    k_bscatter<<<hist_blocks, 256, 0, stream>>>(esrc, edst, bcur, ebuf, E);
    k_fscatter2<<<NB, 256, 0, stream>>>(ebuf, boff, rowptr, soff, N, E);

    // 2. convert input + weights to bf16
    int nq = N * 64 / 4;
    k_f2b<<<(nq + 255) / 256, 256, 0, stream>>>((const float4*)x, (ushort4*)hbA, nq);
    for (int i = 0; i < 4; i++)
        k_wprep<<<32, 256, 0, stream>>>(wroot[i], wrel[i], wt + i * 64 * 128);

    // 3. four conv layers (bf16 h ping-pong, MFMA gemm)
    int agg_blocks = (N * 64 + 255) / 256;   // one wave per node
    int gemm_blocks = (N + 63) / 64;         // 64-node tile per block

    k_agg<<<agg_blocks, 256, 0, stream>>>(hbA, aggb, rowptr, soff, N);
    k_gemm<1><<<gemm_blocks, 256, 0, stream>>>(hbA, aggb, wt + 0 * 8192, brel[0], hbB, N);

    k_agg<<<agg_blocks, 256, 0, stream>>>(hbB, aggb, rowptr, soff, N);
    k_gemm<1><<<gemm_blocks, 256, 0, stream>>>(hbB, aggb, wt + 1 * 8192, brel[1], hbA, N);

    k_agg<<<agg_blocks, 256, 0, stream>>>(hbA, aggb, rowptr, soff, N);
    k_gemm<1><<<gemm_blocks, 256, 0, stream>>>(hbA, aggb, wt + 2 * 8192, brel[2], hbB, N);

    k_agg<<<agg_blocks, 256, 0, stream>>>(hbB, aggb, rowptr, soff, N);
    k_gemm<0><<<gemm_blocks, 256, 0, stream>>>(hbB, aggb, wt + 3 * 8192, brel[3], hbA, N);

    // 4. pooling
    k_bounds<<<(N + 255) / 256, 256, 0, stream>>>(batch, gstart, gend, N);
    k_pool<<<G, 64, 0, stream>>>(hbA, gstart, gend, T, pool);

    // 5. MLP head
    k_mlp<<<G, 256, 0, stream>>>(pool, w1, b1, w2, b2, w3, b3, out);
}